// Round 10
// baseline (408.436 us; speedup 1.0000x reference)
//
#include <hip/hip_runtime.h>
#include <math.h>

#define D 128

typedef __attribute__((ext_vector_type(8))) short short8_t;
typedef __attribute__((ext_vector_type(4))) float f32x4;
typedef __attribute__((ext_vector_type(2))) float f32x2;

__device__ __forceinline__ short f2bf(float f) {
  union { float f; unsigned u; } v; v.f = f;
  unsigned r = v.u + 0x7FFFu + ((v.u >> 16) & 1u);  // round-to-nearest-even
  return (short)(r >> 16);
}
__device__ __forceinline__ float bf2f(unsigned u16) {
  union { unsigned u; float f; } v; v.u = u16 << 16; return v.f;
}

// ---------------------------------------------------------------------------
// prep: Wc = W0@W0 -> bf16 ; W2,Wl -> bf16 ; zero count[] ; zero h
// ---------------------------------------------------------------------------
__global__ void prep_kernel(const float* __restrict__ W0, const float* __restrict__ W2,
                            const float* __restrict__ Wl,
                            short* __restrict__ Wcb, short* __restrict__ W2b,
                            short* __restrict__ Wlb, int* __restrict__ count,
                            float* __restrict__ h, int N, int nb, long h4) {
  int b = blockIdx.x, t = threadIdx.x;
  if (b < 64) {
    int idx = b * 256 + t;
    int r = idx >> 7, c = idx & 127;
    float s = 0.f;
    for (int k = 0; k < D; ++k) s += W0[r * D + k] * W0[k * D + c];
    Wcb[idx] = f2bf(s);
  } else if (b < 128) {
    int idx = (b - 64) * 256 + t;
    W2b[idx] = f2bf(W2[idx]);
  } else if (b < 192) {
    int idx = (b - 128) * 256 + t;
    Wlb[idx] = f2bf(Wl[idx]);
  } else if (b < 192 + nb) {
    int idx = (b - 192) * 256 + t;
    if (idx < N) count[idx] = 0;
  } else {
    long i = (long)(b - 192 - nb) * 256 + t;
    long stride = (long)(gridDim.x - 192 - nb) * 256;
    f32x4 z = {0.f, 0.f, 0.f, 0.f};
    for (; i < h4; i += stride) ((f32x4*)h)[i] = z;
  }
}

// ---------------------------------------------------------------------------
__global__ void hist_kernel(const int* __restrict__ gi, int* __restrict__ count, int E) {
  int t = blockIdx.x * 256 + threadIdx.x;
  int base = t * 4;
  if (base + 3 < E) {
    int4 v = *(const int4*)(gi + base);
    atomicAdd(&count[v.x], 1);
    atomicAdd(&count[v.y], 1);
    atomicAdd(&count[v.z], 1);
    atomicAdd(&count[v.w], 1);
  } else {
    for (int k = base; k < E; ++k) atomicAdd(&count[gi[k]], 1);
  }
}

// ---------------------------------------------------------------------------
__global__ __launch_bounds__(256) void scan_a_kernel(const int* __restrict__ count,
                                                     int* __restrict__ pref,
                                                     int* __restrict__ bsum, int N) {
  __shared__ int ws[4];
  const int tid = threadIdx.x, lane = tid & 63, wave = tid >> 6;
  int i = blockIdx.x * 256 + tid;
  int c = (i < N) ? count[i] : 0;
  int v = c;
#pragma unroll
  for (int o = 1; o < 64; o <<= 1) {
    int u = __shfl_up(v, o, 64);
    if (lane >= o) v += u;
  }
  if (lane == 63) ws[wave] = v;
  __syncthreads();
  int wp = 0;
  for (int w = 0; w < wave; ++w) wp += ws[w];
  if (i < N) pref[i] = wp + v - c;
  if (tid == 255) bsum[blockIdx.x] = wp + v;
}

__global__ __launch_bounds__(256) void scan_c_kernel(const int* __restrict__ pref,
                                                     const int* __restrict__ bsum,
                                                     int* __restrict__ woff, int N) {
  __shared__ int base_s;
  const int tid = threadIdx.x, lane = tid & 63;
  if (tid < 64) {
    int p = 0;
    for (int k = lane; k < blockIdx.x; k += 64) p += bsum[k];
#pragma unroll
    for (int o = 32; o; o >>= 1) p += __shfl_xor(p, o, 64);
    if (lane == 0) base_s = p;
  }
  __syncthreads();
  int i = blockIdx.x * 256 + tid;
  if (i < N) woff[i] = pref[i] + base_s;
}

// ---------------------------------------------------------------------------
__global__ void scatter_kernel(const int* __restrict__ gi, const int* __restrict__ gj,
                               int* __restrict__ woff, int4* __restrict__ edata, int E) {
  int e = blockIdx.x * 256 + threadIdx.x;
  if (e < E) {
    int i = gi[e];
    int pos = atomicAdd(&woff[i], 1);
    int4 ed; ed.x = e; ed.y = gj[e]; ed.z = i; ed.w = 0;
    edata[pos] = ed;
  }
}

// ---------------------------------------------------------------------------
// Wxh = x @ Wl^T + bl -> bf16
// ---------------------------------------------------------------------------
__global__ __launch_bounds__(256, 2) void node_gemm_kernel(
    const float* __restrict__ x, const short* __restrict__ Wlb,
    const float* __restrict__ bl, short* __restrict__ WxhB, int N) {
  __shared__ short Wl_s[D * D];
  const int tid = threadIdx.x;
  const int lane = tid & 63, wave = tid >> 6;
  const int q = lane & 15, g = lane >> 4;

  for (int it = 0; it < 8; ++it) {
    int eoff = (it * 256 + tid) * 8;
    int row = eoff >> 7, col = eoff & 127;
    int scol = col ^ ((row & 7) << 3);
    *(short8_t*)&Wl_s[row * D + scol] = *(const short8_t*)&Wlb[eoff];
  }

  const int rbase = blockIdx.x * 64 + wave * 16;
  int arow = rbase + q; if (arow > N - 1) arow = N - 1;
  short8_t a[4];
  const float* src = x + (size_t)arow * D;
#pragma unroll
  for (int c = 0; c < 4; ++c) {
    int kb = c * 32 + g * 8;
    f32x4 v0 = *(const f32x4*)(src + kb);
    f32x4 v1 = *(const f32x4*)(src + kb + 4);
    short8_t t;
    t[0]=f2bf(v0.x); t[1]=f2bf(v0.y); t[2]=f2bf(v0.z); t[3]=f2bf(v0.w);
    t[4]=f2bf(v1.x); t[5]=f2bf(v1.y); t[6]=f2bf(v1.z); t[7]=f2bf(v1.w);
    a[c] = t;
  }

  __syncthreads();

  f32x4 acc[8];
#pragma unroll
  for (int n = 0; n < 8; ++n) acc[n] = f32x4{0.f, 0.f, 0.f, 0.f};
#pragma unroll
  for (int n = 0; n < 8; ++n) {
    int row = n * 16 + q;
    int sw = (row & 7) << 3;
#pragma unroll
    for (int c = 0; c < 4; ++c) {
      int col = (c * 32 + g * 8) ^ sw;
      short8_t b = *(const short8_t*)&Wl_s[row * D + col];
      acc[n] = __builtin_amdgcn_mfma_f32_16x16x32_bf16(a[c], b, acc[n], 0, 0, 0);
    }
  }

#pragma unroll
  for (int n = 0; n < 8; ++n) {
    int col = n * 16 + q;
    float bias = bl[col];
#pragma unroll
    for (int r = 0; r < 4; ++r) {
      int orow = rbase + g * 4 + r;
      if (orow < N) WxhB[(size_t)orow * D + col] = f2bf(acc[n][r] + bias);
    }
  }
}

// ---------------------------------------------------------------------------
// fused edge kernel v6: 256 threads, 2 blocks/CU, weights in LDS,
// edata 3-deep + rbf 1-deep prefetch (r9), and the reduce now runs DIRECTLY
// in MFMA accumulator layout: lane (g,q) owns m[g*4+rr][n*16+q]; Wxh[j] is
// gathered in the same layout; per-lane segmented accumulation over the 4
// CSR-sorted edge rows, 8 f32 atomics per segment flush. This deletes the
// second LDS round trip (32 ds_write_b16 + 16 ds_read_b32 + 16 shfl per
// tile-wave) and keeps m in f32 end-to-end.
// ---------------------------------------------------------------------------
__global__ __launch_bounds__(256, 2) void fused_edge_kernel(
    const float* __restrict__ rbf, const float* __restrict__ b0v,
    const float* __restrict__ b2v, const short* __restrict__ Wcb,
    const short* __restrict__ W2b, const short* __restrict__ WxhB,
    const int4* __restrict__ edata, float* __restrict__ h, int E, int ntiles) {
  __shared__ short Wc_s[D * D];
  __shared__ short W2_s[D * D];
  __shared__ short m_s[4][16 * D];

  const int tid = threadIdx.x;
  const int lane = tid & 63, wave = tid >> 6;
  const int q = lane & 15, g = lane >> 4;

  for (int it = 0; it < 8; ++it) {
    int eoff = (it * 256 + tid) * 8;
    int row = eoff >> 7, col = eoff & 127;
    int scol = col ^ ((row & 7) << 3);
    *(short8_t*)&Wc_s[row * D + scol] = *(const short8_t*)&Wcb[eoff];
    *(short8_t*)&W2_s[row * D + scol] = *(const short8_t*)&W2b[eoff];
  }

  float b0r[8], b2r[8];
#pragma unroll
  for (int n = 0; n < 8; ++n) { b0r[n] = b0v[n * 16 + q]; b2r[n] = b2v[n * 16 + q]; }

  __syncthreads();

  short* ms = &m_s[wave][0];
  const int stride = gridDim.x;

  int tile = blockIdx.x;
  if (tile >= ntiles) return;

#define EQOF(t) ({ int tc_ = (t) < ntiles ? (t) : ntiles - 1;                  \
                   int e_ = tc_ * 64 + wave * 16 + q;                          \
                   e_ < E ? e_ : E - 1; })

  // prologue: edata 3-deep, rbf for tile t
  int4 ed0 = edata[EQOF(tile)];
  int4 ed1 = edata[EQOF(tile + stride)];
  int4 ed2 = edata[EQOF(tile + 2 * stride)];
  f32x4 rb[8];
  {
    const float* src = rbf + (size_t)ed0.x * D;
#pragma unroll
    for (int c = 0; c < 4; ++c) {
      rb[c * 2]     = *(const f32x4*)(src + c * 32 + g * 8);
      rb[c * 2 + 1] = *(const f32x4*)(src + c * 32 + g * 8 + 4);
    }
  }

  while (true) {
    const bool hnext = (tile + stride) < ntiles;
    const int eb = tile * 64 + wave * 16;

    // this lane's 4 edge rows: j, i, validity
    int jr[4], ir[4];
    bool val[4];
#pragma unroll
    for (int rr = 0; rr < 4; ++rr) {
      jr[rr] = __shfl(ed0.y, g * 4 + rr, 64);
      ir[rr] = __shfl(ed0.z, g * 4 + rr, 64);
      val[rr] = (eb + g * 4 + rr) < E;
    }

    // consume rb(t) -> A fragments
    short8_t a[4];
#pragma unroll
    for (int c = 0; c < 4; ++c) {
      f32x4 v0 = rb[c * 2], v1 = rb[c * 2 + 1];
      short8_t t;
      t[0]=f2bf(v0.x); t[1]=f2bf(v0.y); t[2]=f2bf(v0.z); t[3]=f2bf(v0.w);
      t[4]=f2bf(v1.x); t[5]=f2bf(v1.y); t[6]=f2bf(v1.z); t[7]=f2bf(v1.w);
      a[c] = t;
    }

    // issue next-tile loads (edata 3 ahead, rbf 1 ahead)
    int4 ed3 = edata[EQOF(tile + 3 * stride)];
    {
      const float* src = rbf + (size_t)ed1.x * D;
#pragma unroll
      for (int c = 0; c < 4; ++c) {
        rb[c * 2]     = *(const f32x4*)(src + c * 32 + g * 8);
        rb[c * 2 + 1] = *(const f32x4*)(src + c * 32 + g * 8 + 4);
      }
    }

    // Wxh[j] gather in accumulator layout: wv[rr][n] = Wxh[jr[rr]][n*16+q]
    // (needed only at the flush, a full tile of compute away)
    unsigned short wv[4][8];
#pragma unroll
    for (int rr = 0; rr < 4; ++rr) {
      const short* wrow = WxhB + (size_t)jr[rr] * D + q;
#pragma unroll
      for (int n = 0; n < 8; ++n)
        wv[rr][n] = *(const unsigned short*)(wrow + n * 16);
    }

    // GEMM1: u = rbf @ Wc^T
    f32x4 acc[8];
#pragma unroll
    for (int n = 0; n < 8; ++n) acc[n] = f32x4{0.f, 0.f, 0.f, 0.f};
#pragma unroll
    for (int n = 0; n < 8; ++n) {
      int row = n * 16 + q;
      int sw = (row & 7) << 3;
#pragma unroll
      for (int c = 0; c < 4; ++c) {
        int col = (c * 32 + g * 8) ^ sw;
        short8_t b = *(const short8_t*)&Wc_s[row * D + col];
        acc[n] = __builtin_amdgcn_mfma_f32_16x16x32_bf16(a[c], b, acc[n], 0, 0, 0);
      }
    }

    // silu(u + b0) -> wave-private LDS tile (bf16, swizzled) — round trip 1
#pragma unroll
    for (int n = 0; n < 8; ++n) {
      int col = n * 16 + q;
#pragma unroll
      for (int r = 0; r < 4; ++r) {
        int row = g * 4 + r;
        float u = acc[n][r] + b0r[n];
        float s = u / (1.0f + __expf(-u));
        ms[row * D + (col ^ ((row & 7) << 3))] = f2bf(s);
      }
    }

    // transposed A fragments
    short8_t a2[4];
    {
      int sw = (q & 7) << 3;
#pragma unroll
      for (int c = 0; c < 4; ++c) {
        int col = (c * 32 + g * 8) ^ sw;
        a2[c] = *(const short8_t*)&ms[q * D + col];
      }
    }

    // GEMM2: m = silu(u) @ W2^T (reuse acc)
#pragma unroll
    for (int n = 0; n < 8; ++n) acc[n] = f32x4{0.f, 0.f, 0.f, 0.f};
#pragma unroll
    for (int n = 0; n < 8; ++n) {
      int row = n * 16 + q;
      int sw = (row & 7) << 3;
#pragma unroll
      for (int c = 0; c < 4; ++c) {
        int col = (c * 32 + g * 8) ^ sw;
        short8_t b = *(const short8_t*)&W2_s[row * D + col];
        acc[n] = __builtin_amdgcn_mfma_f32_16x16x32_bf16(a2[c], b, acc[n], 0, 0, 0);
      }
    }

    // segmented accumulate + flush, directly in accumulator layout
    float sum[8];
#pragma unroll
    for (int n = 0; n < 8; ++n) sum[n] = 0.f;
    int cur = -1;
#pragma unroll
    for (int rr = 0; rr < 4; ++rr) {
      if (val[rr]) {
        if (ir[rr] != cur) {
          if (cur >= 0) {
            float* dst = &h[(size_t)cur * D + q];
#pragma unroll
            for (int n = 0; n < 8; ++n) {
              __hip_atomic_fetch_add(dst + n * 16, sum[n],
                                     __ATOMIC_RELAXED, __HIP_MEMORY_SCOPE_AGENT);
              sum[n] = 0.f;
            }
          }
          cur = ir[rr];
        }
#pragma unroll
        for (int n = 0; n < 8; ++n)
          sum[n] += (acc[n][rr] + b2r[n]) * bf2f(wv[rr][n]);
      }
    }
    if (cur >= 0) {
      float* dst = &h[(size_t)cur * D + q];
#pragma unroll
      for (int n = 0; n < 8; ++n)
        __hip_atomic_fetch_add(dst + n * 16, sum[n],
                               __ATOMIC_RELAXED, __HIP_MEMORY_SCOPE_AGENT);
    }

    if (!hnext) break;
    tile += stride;
    ed0 = ed1; ed1 = ed2; ed2 = ed3;
  }
#undef EQOF
}

// ---------------------------------------------------------------------------
// LayerNorm over h = x + agg
// ---------------------------------------------------------------------------
__global__ __launch_bounds__(256) void ln_kernel(const float* __restrict__ agg,
                                                 const float* __restrict__ x,
                                                 const float* __restrict__ gamma,
                                                 const float* __restrict__ beta,
                                                 float* __restrict__ out, int N) {
  int wave = threadIdx.x >> 6, lane = threadIdx.x & 63;
  long row = (long)blockIdx.x * 4 + wave;
  if (row >= N) return;
  int c = lane * 2;
  f32x2 av = *(const f32x2*)&agg[row * D + c];
  f32x2 xv = *(const f32x2*)&x[row * D + c];
  float h0 = av.x + xv.x, h1 = av.y + xv.y;
  float sum = h0 + h1;
  float sq = h0 * h0 + h1 * h1;
#pragma unroll
  for (int o = 32; o; o >>= 1) {
    sum += __shfl_xor(sum, o, 64);
    sq += __shfl_xor(sq, o, 64);
  }
  float mu = sum * (1.0f / 128.0f);
  float var = sq * (1.0f / 128.0f) - mu * mu;
  float rstd = rsqrtf(var + 1e-5f);
  f32x2 gv = *(const f32x2*)&gamma[c];
  f32x2 bv = *(const f32x2*)&beta[c];
  f32x2 ov;
  ov.x = (h0 - mu) * rstd * gv.x + bv.x;
  ov.y = (h1 - mu) * rstd * gv.y + bv.y;
  *(f32x2*)&out[row * D + c] = ov;
}

// ---------------------------------------------------------------------------
extern "C" void kernel_launch(void* const* d_in, const int* in_sizes, int n_in,
                              void* d_out, int out_size, void* d_ws, size_t ws_size,
                              hipStream_t stream) {
  const float* x    = (const float*)d_in[0];
  const int*   gi   = (const int*)d_in[1];
  const int*   gj   = (const int*)d_in[2];
  const float* rbf  = (const float*)d_in[3];
  const float* Wl   = (const float*)d_in[4];
  const float* bl   = (const float*)d_in[5];
  const float* W0   = (const float*)d_in[6];
  const float* b0   = (const float*)d_in[7];
  const float* W2   = (const float*)d_in[8];
  const float* b2   = (const float*)d_in[9];
  const float* gam  = (const float*)d_in[10];
  const float* bet  = (const float*)d_in[11];

  const int N = in_sizes[0] / D;  // 50000
  const int E = in_sizes[1];      // 600000

  char* ws = (char*)d_ws;
  size_t off = 0;
  float* h    = (float*)(ws + off); off += (size_t)N * D * 4;
  short* WxhB = (short*)(ws + off); off += (size_t)N * D * 2;
  int4*  edat = (int4*)(ws + off);  off += (size_t)E * 16;
  int*   cnt  = (int*)(ws + off);   off += (size_t)N * 4;
  int*   pref = (int*)(ws + off);   off += (size_t)N * 4;
  int*   woff = (int*)(ws + off);   off += (size_t)N * 4;
  int*   bsum = (int*)(ws + off);   off += 1024;
  short* Wcb  = (short*)(ws + off); off += D * D * 2;
  short* W2b  = (short*)(ws + off); off += D * D * 2;
  short* Wlb  = (short*)(ws + off); off += D * D * 2;

  const int ntiles = (E + 63) / 64;     // 64 edges per tile (4 waves x 16)
  const int nb = (N + 255) / 256;

  prep_kernel<<<192 + nb + 1024, 256, 0, stream>>>(W0, W2, Wl, Wcb, W2b, Wlb,
                                                   cnt, h, N, nb, (long)N * D / 4);
  hist_kernel<<<(E / 4 + 255) / 256, 256, 0, stream>>>(gi, cnt, E);
  scan_a_kernel<<<nb, 256, 0, stream>>>(cnt, pref, bsum, N);
  scan_c_kernel<<<nb, 256, 0, stream>>>(pref, bsum, woff, N);
  scatter_kernel<<<(E + 255) / 256, 256, 0, stream>>>(gi, gj, woff, edat, E);
  node_gemm_kernel<<<(N + 63) / 64, 256, 0, stream>>>(x, Wlb, bl, WxhB, N);
  fused_edge_kernel<<<512, 256, 0, stream>>>(rbf, b0, b2, Wcb, W2b, WxhB,
                                             edat, h, E, ntiles);
  ln_kernel<<<(N + 3) / 4, 256, 0, stream>>>(h, x, gam, bet, (float*)d_out, N);
}

// Round 11
// 314.815 us; speedup vs baseline: 1.2974x; 1.2974x over previous
//
#include <hip/hip_runtime.h>
#include <math.h>

#define D 128

typedef __attribute__((ext_vector_type(8))) short short8_t;
typedef __attribute__((ext_vector_type(4))) float f32x4;
typedef __attribute__((ext_vector_type(2))) float f32x2;

__device__ __forceinline__ short f2bf(float f) {
  union { float f; unsigned u; } v; v.f = f;
  unsigned r = v.u + 0x7FFFu + ((v.u >> 16) & 1u);  // round-to-nearest-even
  return (short)(r >> 16);
}
__device__ __forceinline__ float bf2f(unsigned u16) {
  union { unsigned u; float f; } v; v.u = u16 << 16; return v.f;
}

// ---------------------------------------------------------------------------
// prep: Wc = W0@W0 -> bf16 ; W2 -> bf16 ; zero count[] ; zero h
// blocks: [0,64) Wc | [64,128) W2 | [128,128+nb) cnt | rest: h
// ---------------------------------------------------------------------------
__global__ void prep_kernel(const float* __restrict__ W0, const float* __restrict__ W2,
                            short* __restrict__ Wcb, short* __restrict__ W2b,
                            int* __restrict__ count, float* __restrict__ h,
                            int N, int nb, long h4) {
  int b = blockIdx.x, t = threadIdx.x;
  if (b < 64) {
    int idx = b * 256 + t;
    int r = idx >> 7, c = idx & 127;
    float s = 0.f;
    for (int k = 0; k < D; ++k) s += W0[r * D + k] * W0[k * D + c];
    Wcb[idx] = f2bf(s);
  } else if (b < 128) {
    int idx = (b - 64) * 256 + t;
    W2b[idx] = f2bf(W2[idx]);
  } else if (b < 128 + nb) {
    int idx = (b - 128) * 256 + t;
    if (idx < N) count[idx] = 0;
  } else {
    long i = (long)(b - 128 - nb) * 256 + t;
    long stride = (long)(gridDim.x - 128 - nb) * 256;
    f32x4 z = {0.f, 0.f, 0.f, 0.f};
    for (; i < h4; i += stride) ((f32x4*)h)[i] = z;
  }
}

// ---------------------------------------------------------------------------
__global__ void hist_kernel(const int* __restrict__ gi, int* __restrict__ count, int E) {
  int t = blockIdx.x * 256 + threadIdx.x;
  int base = t * 4;
  if (base + 3 < E) {
    int4 v = *(const int4*)(gi + base);
    atomicAdd(&count[v.x], 1);
    atomicAdd(&count[v.y], 1);
    atomicAdd(&count[v.z], 1);
    atomicAdd(&count[v.w], 1);
  } else {
    for (int k = base; k < E; ++k) atomicAdd(&count[gi[k]], 1);
  }
}

// ---------------------------------------------------------------------------
__global__ __launch_bounds__(256) void scan_a_kernel(const int* __restrict__ count,
                                                     int* __restrict__ pref,
                                                     int* __restrict__ bsum, int N) {
  __shared__ int ws[4];
  const int tid = threadIdx.x, lane = tid & 63, wave = tid >> 6;
  int i = blockIdx.x * 256 + tid;
  int c = (i < N) ? count[i] : 0;
  int v = c;
#pragma unroll
  for (int o = 1; o < 64; o <<= 1) {
    int u = __shfl_up(v, o, 64);
    if (lane >= o) v += u;
  }
  if (lane == 63) ws[wave] = v;
  __syncthreads();
  int wp = 0;
  for (int w = 0; w < wave; ++w) wp += ws[w];
  if (i < N) pref[i] = wp + v - c;
  if (tid == 255) bsum[blockIdx.x] = wp + v;
}

__global__ __launch_bounds__(256) void scan_c_kernel(const int* __restrict__ pref,
                                                     const int* __restrict__ bsum,
                                                     int* __restrict__ woff, int N) {
  __shared__ int base_s;
  const int tid = threadIdx.x, lane = tid & 63;
  if (tid < 64) {
    int p = 0;
    for (int k = lane; k < blockIdx.x; k += 64) p += bsum[k];
#pragma unroll
    for (int o = 32; o; o >>= 1) p += __shfl_xor(p, o, 64);
    if (lane == 0) base_s = p;
  }
  __syncthreads();
  int i = blockIdx.x * 256 + tid;
  if (i < N) woff[i] = pref[i] + base_s;
}

// ---------------------------------------------------------------------------
__global__ void scatter_kernel(const int* __restrict__ gi, const int* __restrict__ gj,
                               int* __restrict__ woff, int4* __restrict__ edata, int E) {
  int e = blockIdx.x * 256 + threadIdx.x;
  if (e < E) {
    int i = gi[e];
    int pos = atomicAdd(&woff[i], 1);
    int4 ed; ed.x = e; ed.y = gj[e]; ed.z = i; ed.w = 0;
    edata[pos] = ed;
  }
}

// ---------------------------------------------------------------------------
// Wxh = x @ Wl^T + bl -> bf16  (stages Wl from f32 directly, converting)
// ---------------------------------------------------------------------------
__global__ __launch_bounds__(256, 2) void node_gemm_kernel(
    const float* __restrict__ x, const float* __restrict__ Wl,
    const float* __restrict__ bl, short* __restrict__ WxhB, int N) {
  __shared__ short Wl_s[D * D];
  const int tid = threadIdx.x;
  const int lane = tid & 63, wave = tid >> 6;
  const int q = lane & 15, g = lane >> 4;

  for (int it = 0; it < 8; ++it) {
    int eoff = (it * 256 + tid) * 8;
    int row = eoff >> 7, col = eoff & 127;
    int scol = col ^ ((row & 7) << 3);
    f32x4 v0 = *(const f32x4*)&Wl[eoff];
    f32x4 v1 = *(const f32x4*)&Wl[eoff + 4];
    short8_t t;
    t[0]=f2bf(v0.x); t[1]=f2bf(v0.y); t[2]=f2bf(v0.z); t[3]=f2bf(v0.w);
    t[4]=f2bf(v1.x); t[5]=f2bf(v1.y); t[6]=f2bf(v1.z); t[7]=f2bf(v1.w);
    *(short8_t*)&Wl_s[row * D + scol] = t;
  }

  const int rbase = blockIdx.x * 64 + wave * 16;
  int arow = rbase + q; if (arow > N - 1) arow = N - 1;
  short8_t a[4];
  const float* src = x + (size_t)arow * D;
#pragma unroll
  for (int c = 0; c < 4; ++c) {
    int kb = c * 32 + g * 8;
    f32x4 v0 = *(const f32x4*)(src + kb);
    f32x4 v1 = *(const f32x4*)(src + kb + 4);
    short8_t t;
    t[0]=f2bf(v0.x); t[1]=f2bf(v0.y); t[2]=f2bf(v0.z); t[3]=f2bf(v0.w);
    t[4]=f2bf(v1.x); t[5]=f2bf(v1.y); t[6]=f2bf(v1.z); t[7]=f2bf(v1.w);
    a[c] = t;
  }

  __syncthreads();

  f32x4 acc[8];
#pragma unroll
  for (int n = 0; n < 8; ++n) acc[n] = f32x4{0.f, 0.f, 0.f, 0.f};
#pragma unroll
  for (int n = 0; n < 8; ++n) {
    int row = n * 16 + q;
    int sw = (row & 7) << 3;
#pragma unroll
    for (int c = 0; c < 4; ++c) {
      int col = (c * 32 + g * 8) ^ sw;
      short8_t b = *(const short8_t*)&Wl_s[row * D + col];
      acc[n] = __builtin_amdgcn_mfma_f32_16x16x32_bf16(a[c], b, acc[n], 0, 0, 0);
    }
  }

#pragma unroll
  for (int n = 0; n < 8; ++n) {
    int col = n * 16 + q;
    float bias = bl[col];
#pragma unroll
    for (int r = 0; r < 4; ++r) {
      int orow = rbase + g * 4 + r;
      if (orow < N) WxhB[(size_t)orow * D + col] = f2bf(acc[n][r] + bias);
    }
  }
}

// ---------------------------------------------------------------------------
// fused edge kernel v7 = r9 structure + Wc register cache:
// GEMM1's B-fragments (loop-invariant Wc rows) live in 128 VGPRs, loaded once
// from global at kernel start — deletes 32 ds_read_b128 per tile and Wc_s
// (LDS 80 -> 48 KB). At 2 blocks/CU (8 waves/CU) the per-wave budget is 256
// VGPR, of which r10 used only 128 — this spends the idle half.
// Reduce path = r9's (LDS transpose + coalesced Wxh gather + 2 atomics/seg).
// ---------------------------------------------------------------------------
__global__ __launch_bounds__(256, 2) void fused_edge_kernel(
    const float* __restrict__ rbf, const float* __restrict__ b0v,
    const float* __restrict__ b2v, const short* __restrict__ Wcb,
    const short* __restrict__ W2b, const short* __restrict__ WxhB,
    const int4* __restrict__ edata, float* __restrict__ h, int E, int ntiles) {
  __shared__ short W2_s[D * D];
  __shared__ short m_s[4][16 * D];

  const int tid = threadIdx.x;
  const int lane = tid & 63, wave = tid >> 6;
  const int q = lane & 15, g = lane >> 4;

  // stage W2 (bf16, XOR-swizzled)
  for (int it = 0; it < 8; ++it) {
    int eoff = (it * 256 + tid) * 8;
    int row = eoff >> 7, col = eoff & 127;
    int scol = col ^ ((row & 7) << 3);
    *(short8_t*)&W2_s[row * D + scol] = *(const short8_t*)&W2b[eoff];
  }

  // Wc B-fragments -> registers (loop-invariant; 32 frags x 4 VGPR = 128)
  short8_t wcf[8][4];
#pragma unroll
  for (int n = 0; n < 8; ++n) {
    const short* wrow = Wcb + (n * 16 + q) * D + g * 8;
#pragma unroll
    for (int c = 0; c < 4; ++c)
      wcf[n][c] = *(const short8_t*)(wrow + c * 32);
  }

  float b0r[8], b2r[8];
#pragma unroll
  for (int n = 0; n < 8; ++n) { b0r[n] = b0v[n * 16 + q]; b2r[n] = b2v[n * 16 + q]; }

  __syncthreads();

  short* ms = &m_s[wave][0];
  const int stride = gridDim.x;

  int tile = blockIdx.x;
  if (tile >= ntiles) return;

#define EQOF(t) ({ int tc_ = (t) < ntiles ? (t) : ntiles - 1;                  \
                   int e_ = tc_ * 64 + wave * 16 + q;                          \
                   e_ < E ? e_ : E - 1; })

  // prologue: edata 3-deep, rbf + Wxh 1-deep (for tile t)
  int4 ed0 = edata[EQOF(tile)];
  int4 ed1 = edata[EQOF(tile + stride)];
  int4 ed2 = edata[EQOF(tile + 2 * stride)];
  f32x4 rb[8];
  {
    const float* src = rbf + (size_t)ed0.x * D;
#pragma unroll
    for (int c = 0; c < 4; ++c) {
      rb[c * 2]     = *(const f32x4*)(src + c * 32 + g * 8);
      rb[c * 2 + 1] = *(const f32x4*)(src + c * 32 + g * 8 + 4);
    }
  }
  unsigned wv0[16];
#pragma unroll
  for (int r = 0; r < 16; ++r) {
    int jr = __shfl(ed0.y, r, 64);
    wv0[r] = *(const unsigned*)&WxhB[(size_t)jr * D + lane * 2];
  }

  while (true) {
    const bool hnext = (tile + stride) < ntiles;

    // consume rb(t) -> A fragments
    short8_t a[4];
#pragma unroll
    for (int c = 0; c < 4; ++c) {
      f32x4 v0 = rb[c * 2], v1 = rb[c * 2 + 1];
      short8_t t;
      t[0]=f2bf(v0.x); t[1]=f2bf(v0.y); t[2]=f2bf(v0.z); t[3]=f2bf(v0.w);
      t[4]=f2bf(v1.x); t[5]=f2bf(v1.y); t[6]=f2bf(v1.z); t[7]=f2bf(v1.w);
      a[c] = t;
    }

    // issue next-tile loads (edata 3 ahead, rbf/Wxh 1 ahead)
    int4 ed3 = edata[EQOF(tile + 3 * stride)];
    {
      const float* src = rbf + (size_t)ed1.x * D;
#pragma unroll
      for (int c = 0; c < 4; ++c) {
        rb[c * 2]     = *(const f32x4*)(src + c * 32 + g * 8);
        rb[c * 2 + 1] = *(const f32x4*)(src + c * 32 + g * 8 + 4);
      }
    }
    unsigned wv1[16];
#pragma unroll
    for (int r = 0; r < 16; ++r) {
      int jr = __shfl(ed1.y, r, 64);
      wv1[r] = *(const unsigned*)&WxhB[(size_t)jr * D + lane * 2];
    }

    // GEMM1: u = rbf @ Wc^T — B from registers, no LDS
    f32x4 acc[8];
#pragma unroll
    for (int n = 0; n < 8; ++n) acc[n] = f32x4{0.f, 0.f, 0.f, 0.f};
#pragma unroll
    for (int n = 0; n < 8; ++n)
#pragma unroll
      for (int c = 0; c < 4; ++c)
        acc[n] = __builtin_amdgcn_mfma_f32_16x16x32_bf16(a[c], wcf[n][c], acc[n], 0, 0, 0);

    // silu(u + b0) -> wave-private LDS tile (bf16, swizzled)
#pragma unroll
    for (int n = 0; n < 8; ++n) {
      int col = n * 16 + q;
#pragma unroll
      for (int r = 0; r < 4; ++r) {
        int row = g * 4 + r;
        float u = acc[n][r] + b0r[n];
        float s = u / (1.0f + __expf(-u));
        ms[row * D + (col ^ ((row & 7) << 3))] = f2bf(s);
      }
    }

    // transposed A fragments
    short8_t a2[4];
    {
      int sw = (q & 7) << 3;
#pragma unroll
      for (int c = 0; c < 4; ++c) {
        int col = (c * 32 + g * 8) ^ sw;
        a2[c] = *(const short8_t*)&ms[q * D + col];
      }
    }

    // GEMM2: m = silu(u) @ W2^T (reuse acc)
#pragma unroll
    for (int n = 0; n < 8; ++n) acc[n] = f32x4{0.f, 0.f, 0.f, 0.f};
#pragma unroll
    for (int n = 0; n < 8; ++n) {
      int row = n * 16 + q;
      int sw = (row & 7) << 3;
#pragma unroll
      for (int c = 0; c < 4; ++c) {
        int col = (c * 32 + g * 8) ^ sw;
        short8_t b = *(const short8_t*)&W2_s[row * D + col];
        acc[n] = __builtin_amdgcn_mfma_f32_16x16x32_bf16(a2[c], b, acc[n], 0, 0, 0);
      }
    }

    // m + b2 -> bf16 back into the wave tile
#pragma unroll
    for (int n = 0; n < 8; ++n) {
      int col = n * 16 + q;
#pragma unroll
      for (int r = 0; r < 4; ++r) {
        int row = g * 4 + r;
        ms[row * D + (col ^ ((row & 7) << 3))] = f2bf(acc[n][r] + b2r[n]);
      }
    }

    // segmented reduce with wv0/ed0 (rows sorted by destination i)
    const int eb = tile * 64 + wave * 16;
    int nv = E - eb; if (nv > 16) nv = 16;
    float a0 = 0.f, a1 = 0.f;
    int cur = -1;
#pragma unroll
    for (int r = 0; r < 16; ++r) {
      if (r < nv) {
        int ir = __shfl(ed0.z, r, 64);
        if (ir != cur) {
          if (cur >= 0) {
            float* dst = &h[(size_t)cur * D + lane * 2];
            __hip_atomic_fetch_add(dst, a0, __ATOMIC_RELAXED, __HIP_MEMORY_SCOPE_AGENT);
            __hip_atomic_fetch_add(dst + 1, a1, __ATOMIC_RELAXED, __HIP_MEMORY_SCOPE_AGENT);
            a0 = a1 = 0.f;
          }
          cur = ir;
        }
        unsigned mv = *(const unsigned*)&ms[r * D + ((lane * 2) ^ ((r & 7) << 3))];
        a0 += bf2f(mv & 0xffffu) * bf2f(wv0[r] & 0xffffu);
        a1 += bf2f(mv >> 16) * bf2f(wv0[r] >> 16);
      }
    }
    if (cur >= 0) {
      float* dst = &h[(size_t)cur * D + lane * 2];
      __hip_atomic_fetch_add(dst, a0, __ATOMIC_RELAXED, __HIP_MEMORY_SCOPE_AGENT);
      __hip_atomic_fetch_add(dst + 1, a1, __ATOMIC_RELAXED, __HIP_MEMORY_SCOPE_AGENT);
    }

    if (!hnext) break;
    tile += stride;
    ed0 = ed1; ed1 = ed2; ed2 = ed3;
#pragma unroll
    for (int r = 0; r < 16; ++r) wv0[r] = wv1[r];
  }
#undef EQOF
}

// ---------------------------------------------------------------------------
// LayerNorm over h = x + agg
// ---------------------------------------------------------------------------
__global__ __launch_bounds__(256) void ln_kernel(const float* __restrict__ agg,
                                                 const float* __restrict__ x,
                                                 const float* __restrict__ gamma,
                                                 const float* __restrict__ beta,
                                                 float* __restrict__ out, int N) {
  int wave = threadIdx.x >> 6, lane = threadIdx.x & 63;
  long row = (long)blockIdx.x * 4 + wave;
  if (row >= N) return;
  int c = lane * 2;
  f32x2 av = *(const f32x2*)&agg[row * D + c];
  f32x2 xv = *(const f32x2*)&x[row * D + c];
  float h0 = av.x + xv.x, h1 = av.y + xv.y;
  float sum = h0 + h1;
  float sq = h0 * h0 + h1 * h1;
#pragma unroll
  for (int o = 32; o; o >>= 1) {
    sum += __shfl_xor(sum, o, 64);
    sq += __shfl_xor(sq, o, 64);
  }
  float mu = sum * (1.0f / 128.0f);
  float var = sq * (1.0f / 128.0f) - mu * mu;
  float rstd = rsqrtf(var + 1e-5f);
  f32x2 gv = *(const f32x2*)&gamma[c];
  f32x2 bv = *(const f32x2*)&beta[c];
  f32x2 ov;
  ov.x = (h0 - mu) * rstd * gv.x + bv.x;
  ov.y = (h1 - mu) * rstd * gv.y + bv.y;
  *(f32x2*)&out[row * D + c] = ov;
}

// ---------------------------------------------------------------------------
extern "C" void kernel_launch(void* const* d_in, const int* in_sizes, int n_in,
                              void* d_out, int out_size, void* d_ws, size_t ws_size,
                              hipStream_t stream) {
  const float* x    = (const float*)d_in[0];
  const int*   gi   = (const int*)d_in[1];
  const int*   gj   = (const int*)d_in[2];
  const float* rbf  = (const float*)d_in[3];
  const float* Wl   = (const float*)d_in[4];
  const float* bl   = (const float*)d_in[5];
  const float* W0   = (const float*)d_in[6];
  const float* b0   = (const float*)d_in[7];
  const float* W2   = (const float*)d_in[8];
  const float* b2   = (const float*)d_in[9];
  const float* gam  = (const float*)d_in[10];
  const float* bet  = (const float*)d_in[11];

  const int N = in_sizes[0] / D;  // 50000
  const int E = in_sizes[1];      // 600000

  char* ws = (char*)d_ws;
  size_t off = 0;
  float* h    = (float*)(ws + off); off += (size_t)N * D * 4;
  short* WxhB = (short*)(ws + off); off += (size_t)N * D * 2;
  int4*  edat = (int4*)(ws + off);  off += (size_t)E * 16;
  int*   cnt  = (int*)(ws + off);   off += (size_t)N * 4;
  int*   pref = (int*)(ws + off);   off += (size_t)N * 4;
  int*   woff = (int*)(ws + off);   off += (size_t)N * 4;
  int*   bsum = (int*)(ws + off);   off += 1024;
  short* Wcb  = (short*)(ws + off); off += D * D * 2;
  short* W2b  = (short*)(ws + off); off += D * D * 2;

  const int ntiles = (E + 63) / 64;     // 64 edges per tile (4 waves x 16)
  const int nb = (N + 255) / 256;

  prep_kernel<<<128 + nb + 1024, 256, 0, stream>>>(W0, W2, Wcb, W2b,
                                                   cnt, h, N, nb, (long)N * D / 4);
  hist_kernel<<<(E / 4 + 255) / 256, 256, 0, stream>>>(gi, cnt, E);
  scan_a_kernel<<<nb, 256, 0, stream>>>(cnt, pref, bsum, N);
  scan_c_kernel<<<nb, 256, 0, stream>>>(pref, bsum, woff, N);
  scatter_kernel<<<(E + 255) / 256, 256, 0, stream>>>(gi, gj, woff, edat, E);
  node_gemm_kernel<<<(N + 63) / 64, 256, 0, stream>>>(x, Wl, bl, WxhB, N);
  fused_edge_kernel<<<512, 256, 0, stream>>>(rbf, b0, b2, Wcb, W2b, WxhB,
                                             edat, h, E, ntiles);
  ln_kernel<<<(N + 3) / 4, 256, 0, stream>>>(h, x, gam, bet, (float*)d_out, N);
}

// Round 12
// 231.597 us; speedup vs baseline: 1.7636x; 1.3593x over previous
//
#include <hip/hip_runtime.h>
#include <math.h>

#define D 128

typedef __attribute__((ext_vector_type(8))) short short8_t;
typedef __attribute__((ext_vector_type(4))) float f32x4;
typedef __attribute__((ext_vector_type(2))) float f32x2;

__device__ __forceinline__ short f2bf(float f) {
  union { float f; unsigned u; } v; v.f = f;
  unsigned r = v.u + 0x7FFFu + ((v.u >> 16) & 1u);  // round-to-nearest-even
  return (short)(r >> 16);
}
__device__ __forceinline__ float bf2f(unsigned u16) {
  union { unsigned u; float f; } v; v.u = u16 << 16; return v.f;
}
// packed f32x2 -> bf16x2 (hardware, 1 instr; dst.lo=cvt(a), dst.hi=cvt(b))
__device__ __forceinline__ unsigned cvt_pk_bf16(float a, float b) {
  unsigned r;
  asm("v_cvt_pk_bf16_f32 %0, %1, %2" : "=v"(r) : "v"(a), "v"(b));
  return r;
}
typedef union { short8_t s8; unsigned u[4]; } pk8;

// ---------------------------------------------------------------------------
// prep: Wc = W0@W0 -> bf16 ; W2 -> bf16 ; zero count[] ; zero h
// ---------------------------------------------------------------------------
__global__ void prep_kernel(const float* __restrict__ W0, const float* __restrict__ W2,
                            short* __restrict__ Wcb, short* __restrict__ W2b,
                            int* __restrict__ count, float* __restrict__ h,
                            int N, int nb, long h4) {
  int b = blockIdx.x, t = threadIdx.x;
  if (b < 64) {
    int idx = b * 256 + t;
    int r = idx >> 7, c = idx & 127;
    float s = 0.f;
    for (int k = 0; k < D; ++k) s += W0[r * D + k] * W0[k * D + c];
    Wcb[idx] = f2bf(s);
  } else if (b < 128) {
    int idx = (b - 64) * 256 + t;
    W2b[idx] = f2bf(W2[idx]);
  } else if (b < 128 + nb) {
    int idx = (b - 128) * 256 + t;
    if (idx < N) count[idx] = 0;
  } else {
    long i = (long)(b - 128 - nb) * 256 + t;
    long stride = (long)(gridDim.x - 128 - nb) * 256;
    f32x4 z = {0.f, 0.f, 0.f, 0.f};
    for (; i < h4; i += stride) ((f32x4*)h)[i] = z;
  }
}

// ---------------------------------------------------------------------------
__global__ void hist_kernel(const int* __restrict__ gi, int* __restrict__ count, int E) {
  int t = blockIdx.x * 256 + threadIdx.x;
  int base = t * 4;
  if (base + 3 < E) {
    int4 v = *(const int4*)(gi + base);
    atomicAdd(&count[v.x], 1);
    atomicAdd(&count[v.y], 1);
    atomicAdd(&count[v.z], 1);
    atomicAdd(&count[v.w], 1);
  } else {
    for (int k = base; k < E; ++k) atomicAdd(&count[gi[k]], 1);
  }
}

// ---------------------------------------------------------------------------
__global__ __launch_bounds__(256) void scan_a_kernel(const int* __restrict__ count,
                                                     int* __restrict__ pref,
                                                     int* __restrict__ bsum, int N) {
  __shared__ int ws[4];
  const int tid = threadIdx.x, lane = tid & 63, wave = tid >> 6;
  int i = blockIdx.x * 256 + tid;
  int c = (i < N) ? count[i] : 0;
  int v = c;
#pragma unroll
  for (int o = 1; o < 64; o <<= 1) {
    int u = __shfl_up(v, o, 64);
    if (lane >= o) v += u;
  }
  if (lane == 63) ws[wave] = v;
  __syncthreads();
  int wp = 0;
  for (int w = 0; w < wave; ++w) wp += ws[w];
  if (i < N) pref[i] = wp + v - c;
  if (tid == 255) bsum[blockIdx.x] = wp + v;
}

__global__ __launch_bounds__(256) void scan_c_kernel(const int* __restrict__ pref,
                                                     const int* __restrict__ bsum,
                                                     int* __restrict__ woff, int N) {
  __shared__ int base_s;
  const int tid = threadIdx.x, lane = tid & 63;
  if (tid < 64) {
    int p = 0;
    for (int k = lane; k < blockIdx.x; k += 64) p += bsum[k];
#pragma unroll
    for (int o = 32; o; o >>= 1) p += __shfl_xor(p, o, 64);
    if (lane == 0) base_s = p;
  }
  __syncthreads();
  int i = blockIdx.x * 256 + tid;
  if (i < N) woff[i] = pref[i] + base_s;
}

// ---------------------------------------------------------------------------
__global__ void scatter_kernel(const int* __restrict__ gi, const int* __restrict__ gj,
                               int* __restrict__ woff, int4* __restrict__ edata, int E) {
  int e = blockIdx.x * 256 + threadIdx.x;
  if (e < E) {
    int i = gi[e];
    int pos = atomicAdd(&woff[i], 1);
    int4 ed; ed.x = e; ed.y = gj[e]; ed.z = i; ed.w = 0;
    edata[pos] = ed;
  }
}

// ---------------------------------------------------------------------------
// Wxh = x @ Wl^T + bl -> bf16  (stages Wl from f32 directly, converting)
// ---------------------------------------------------------------------------
__global__ __launch_bounds__(256, 2) void node_gemm_kernel(
    const float* __restrict__ x, const float* __restrict__ Wl,
    const float* __restrict__ bl, short* __restrict__ WxhB, int N) {
  __shared__ short Wl_s[D * D];
  const int tid = threadIdx.x;
  const int lane = tid & 63, wave = tid >> 6;
  const int q = lane & 15, g = lane >> 4;

  for (int it = 0; it < 8; ++it) {
    int eoff = (it * 256 + tid) * 8;
    int row = eoff >> 7, col = eoff & 127;
    int scol = col ^ ((row & 7) << 3);
    f32x4 v0 = *(const f32x4*)&Wl[eoff];
    f32x4 v1 = *(const f32x4*)&Wl[eoff + 4];
    pk8 t;
    t.u[0] = cvt_pk_bf16(v0.x, v0.y); t.u[1] = cvt_pk_bf16(v0.z, v0.w);
    t.u[2] = cvt_pk_bf16(v1.x, v1.y); t.u[3] = cvt_pk_bf16(v1.z, v1.w);
    *(short8_t*)&Wl_s[row * D + scol] = t.s8;
  }

  const int rbase = blockIdx.x * 64 + wave * 16;
  int arow = rbase + q; if (arow > N - 1) arow = N - 1;
  short8_t a[4];
  const float* src = x + (size_t)arow * D;
#pragma unroll
  for (int c = 0; c < 4; ++c) {
    int kb = c * 32 + g * 8;
    f32x4 v0 = *(const f32x4*)(src + kb);
    f32x4 v1 = *(const f32x4*)(src + kb + 4);
    pk8 t;
    t.u[0] = cvt_pk_bf16(v0.x, v0.y); t.u[1] = cvt_pk_bf16(v0.z, v0.w);
    t.u[2] = cvt_pk_bf16(v1.x, v1.y); t.u[3] = cvt_pk_bf16(v1.z, v1.w);
    a[c] = t.s8;
  }

  __syncthreads();

  f32x4 acc[8];
#pragma unroll
  for (int n = 0; n < 8; ++n) acc[n] = f32x4{0.f, 0.f, 0.f, 0.f};
#pragma unroll
  for (int n = 0; n < 8; ++n) {
    int row = n * 16 + q;
    int sw = (row & 7) << 3;
#pragma unroll
    for (int c = 0; c < 4; ++c) {
      int col = (c * 32 + g * 8) ^ sw;
      short8_t b = *(const short8_t*)&Wl_s[row * D + col];
      acc[n] = __builtin_amdgcn_mfma_f32_16x16x32_bf16(a[c], b, acc[n], 0, 0, 0);
    }
  }

#pragma unroll
  for (int n = 0; n < 8; ++n) {
    int col = n * 16 + q;
    float bias = bl[col];
#pragma unroll
    for (int r = 0; r < 4; ++r) {
      int orow = rbase + g * 4 + r;
      if (orow < N) WxhB[(size_t)orow * D + col] = f2bf(acc[n][r] + bias);
    }
  }
}

// ---------------------------------------------------------------------------
// fused edge kernel v8 = r9 structure (both weights in LDS, edata 3-deep +
// rbf/Wxh 1-deep prefetch) + VALU cut: packed v_cvt_pk_bf16_f32 conversions
// (128->16 ops for rbf, 16->4 per n for silu/m) and silu via v_rcp instead of
// exact division. r11 lesson: allocator pins 128 VGPR — keep reg pressure low,
// weights stay in LDS.
// ---------------------------------------------------------------------------
__global__ __launch_bounds__(256, 2) void fused_edge_kernel(
    const float* __restrict__ rbf, const float* __restrict__ b0v,
    const float* __restrict__ b2v, const short* __restrict__ Wcb,
    const short* __restrict__ W2b, const short* __restrict__ WxhB,
    const int4* __restrict__ edata, float* __restrict__ h, int E, int ntiles) {
  __shared__ short Wc_s[D * D];
  __shared__ short W2_s[D * D];
  __shared__ short m_s[4][16 * D];

  const int tid = threadIdx.x;
  const int lane = tid & 63, wave = tid >> 6;
  const int q = lane & 15, g = lane >> 4;

  for (int it = 0; it < 8; ++it) {
    int eoff = (it * 256 + tid) * 8;
    int row = eoff >> 7, col = eoff & 127;
    int scol = col ^ ((row & 7) << 3);
    *(short8_t*)&Wc_s[row * D + scol] = *(const short8_t*)&Wcb[eoff];
    *(short8_t*)&W2_s[row * D + scol] = *(const short8_t*)&W2b[eoff];
  }

  float b0r[8], b2r[8];
#pragma unroll
  for (int n = 0; n < 8; ++n) { b0r[n] = b0v[n * 16 + q]; b2r[n] = b2v[n * 16 + q]; }

  __syncthreads();

  short* ms = &m_s[wave][0];
  const int stride = gridDim.x;

  int tile = blockIdx.x;
  if (tile >= ntiles) return;

#define EQOF(t) ({ int tc_ = (t) < ntiles ? (t) : ntiles - 1;                  \
                   int e_ = tc_ * 64 + wave * 16 + q;                          \
                   e_ < E ? e_ : E - 1; })

  // prologue: edata 3-deep, rbf + Wxh 1-deep (for tile t)
  int4 ed0 = edata[EQOF(tile)];
  int4 ed1 = edata[EQOF(tile + stride)];
  int4 ed2 = edata[EQOF(tile + 2 * stride)];
  f32x4 rb[8];
  {
    const float* src = rbf + (size_t)ed0.x * D;
#pragma unroll
    for (int c = 0; c < 4; ++c) {
      rb[c * 2]     = *(const f32x4*)(src + c * 32 + g * 8);
      rb[c * 2 + 1] = *(const f32x4*)(src + c * 32 + g * 8 + 4);
    }
  }
  unsigned wv0[16];
#pragma unroll
  for (int r = 0; r < 16; ++r) {
    int jr = __shfl(ed0.y, r, 64);
    wv0[r] = *(const unsigned*)&WxhB[(size_t)jr * D + lane * 2];
  }

  while (true) {
    const bool hnext = (tile + stride) < ntiles;

    // consume rb(t) -> A fragments (packed hw conversion)
    short8_t a[4];
#pragma unroll
    for (int c = 0; c < 4; ++c) {
      f32x4 v0 = rb[c * 2], v1 = rb[c * 2 + 1];
      pk8 t;
      t.u[0] = cvt_pk_bf16(v0.x, v0.y); t.u[1] = cvt_pk_bf16(v0.z, v0.w);
      t.u[2] = cvt_pk_bf16(v1.x, v1.y); t.u[3] = cvt_pk_bf16(v1.z, v1.w);
      a[c] = t.s8;
    }

    // issue next-tile loads (edata 3 ahead, rbf/Wxh 1 ahead)
    int4 ed3 = edata[EQOF(tile + 3 * stride)];
    {
      const float* src = rbf + (size_t)ed1.x * D;
#pragma unroll
      for (int c = 0; c < 4; ++c) {
        rb[c * 2]     = *(const f32x4*)(src + c * 32 + g * 8);
        rb[c * 2 + 1] = *(const f32x4*)(src + c * 32 + g * 8 + 4);
      }
    }
    unsigned wv1[16];
#pragma unroll
    for (int r = 0; r < 16; ++r) {
      int jr = __shfl(ed1.y, r, 64);
      wv1[r] = *(const unsigned*)&WxhB[(size_t)jr * D + lane * 2];
    }

    // GEMM1: u = rbf @ Wc^T
    f32x4 acc[8];
#pragma unroll
    for (int n = 0; n < 8; ++n) acc[n] = f32x4{0.f, 0.f, 0.f, 0.f};
#pragma unroll
    for (int n = 0; n < 8; ++n) {
      int row = n * 16 + q;
      int sw = (row & 7) << 3;
#pragma unroll
      for (int c = 0; c < 4; ++c) {
        int col = (c * 32 + g * 8) ^ sw;
        short8_t b = *(const short8_t*)&Wc_s[row * D + col];
        acc[n] = __builtin_amdgcn_mfma_f32_16x16x32_bf16(a[c], b, acc[n], 0, 0, 0);
      }
    }

    // silu(u + b0) -> wave-private LDS tile (bf16, swizzled); rcp + packed cvt
#pragma unroll
    for (int n = 0; n < 8; ++n) {
      int col = n * 16 + q;
      float s[4];
#pragma unroll
      for (int r = 0; r < 4; ++r) {
        float u = acc[n][r] + b0r[n];
        s[r] = u * __builtin_amdgcn_rcpf(1.0f + __expf(-u));
      }
      unsigned p01 = cvt_pk_bf16(s[0], s[1]);
      unsigned p23 = cvt_pk_bf16(s[2], s[3]);
      int r0 = g * 4;
      ms[(r0 + 0) * D + (col ^ (((r0 + 0) & 7) << 3))] = (short)p01;
      ms[(r0 + 1) * D + (col ^ (((r0 + 1) & 7) << 3))] = (short)(p01 >> 16);
      ms[(r0 + 2) * D + (col ^ (((r0 + 2) & 7) << 3))] = (short)p23;
      ms[(r0 + 3) * D + (col ^ (((r0 + 3) & 7) << 3))] = (short)(p23 >> 16);
    }

    // transposed A fragments
    short8_t a2[4];
    {
      int sw = (q & 7) << 3;
#pragma unroll
      for (int c = 0; c < 4; ++c) {
        int col = (c * 32 + g * 8) ^ sw;
        a2[c] = *(const short8_t*)&ms[q * D + col];
      }
    }

    // GEMM2: m = silu(u) @ W2^T (reuse acc)
#pragma unroll
    for (int n = 0; n < 8; ++n) acc[n] = f32x4{0.f, 0.f, 0.f, 0.f};
#pragma unroll
    for (int n = 0; n < 8; ++n) {
      int row = n * 16 + q;
      int sw = (row & 7) << 3;
#pragma unroll
      for (int c = 0; c < 4; ++c) {
        int col = (c * 32 + g * 8) ^ sw;
        short8_t b = *(const short8_t*)&W2_s[row * D + col];
        acc[n] = __builtin_amdgcn_mfma_f32_16x16x32_bf16(a2[c], b, acc[n], 0, 0, 0);
      }
    }

    // m + b2 -> bf16 back into the wave tile (packed cvt)
#pragma unroll
    for (int n = 0; n < 8; ++n) {
      int col = n * 16 + q;
      unsigned p01 = cvt_pk_bf16(acc[n][0] + b2r[n], acc[n][1] + b2r[n]);
      unsigned p23 = cvt_pk_bf16(acc[n][2] + b2r[n], acc[n][3] + b2r[n]);
      int r0 = g * 4;
      ms[(r0 + 0) * D + (col ^ (((r0 + 0) & 7) << 3))] = (short)p01;
      ms[(r0 + 1) * D + (col ^ (((r0 + 1) & 7) << 3))] = (short)(p01 >> 16);
      ms[(r0 + 2) * D + (col ^ (((r0 + 2) & 7) << 3))] = (short)p23;
      ms[(r0 + 3) * D + (col ^ (((r0 + 3) & 7) << 3))] = (short)(p23 >> 16);
    }

    // segmented reduce with wv0/ed0 (rows sorted by destination i)
    const int eb = tile * 64 + wave * 16;
    int nv = E - eb; if (nv > 16) nv = 16;
    float a0 = 0.f, a1 = 0.f;
    int cur = -1;
#pragma unroll
    for (int r = 0; r < 16; ++r) {
      if (r < nv) {
        int ir = __shfl(ed0.z, r, 64);
        if (ir != cur) {
          if (cur >= 0) {
            float* dst = &h[(size_t)cur * D + lane * 2];
            __hip_atomic_fetch_add(dst, a0, __ATOMIC_RELAXED, __HIP_MEMORY_SCOPE_AGENT);
            __hip_atomic_fetch_add(dst + 1, a1, __ATOMIC_RELAXED, __HIP_MEMORY_SCOPE_AGENT);
            a0 = a1 = 0.f;
          }
          cur = ir;
        }
        unsigned mv = *(const unsigned*)&ms[r * D + ((lane * 2) ^ ((r & 7) << 3))];
        a0 += bf2f(mv & 0xffffu) * bf2f(wv0[r] & 0xffffu);
        a1 += bf2f(mv >> 16) * bf2f(wv0[r] >> 16);
      }
    }
    if (cur >= 0) {
      float* dst = &h[(size_t)cur * D + lane * 2];
      __hip_atomic_fetch_add(dst, a0, __ATOMIC_RELAXED, __HIP_MEMORY_SCOPE_AGENT);
      __hip_atomic_fetch_add(dst + 1, a1, __ATOMIC_RELAXED, __HIP_MEMORY_SCOPE_AGENT);
    }

    if (!hnext) break;
    tile += stride;
    ed0 = ed1; ed1 = ed2; ed2 = ed3;
#pragma unroll
    for (int r = 0; r < 16; ++r) wv0[r] = wv1[r];
  }
#undef EQOF
}

// ---------------------------------------------------------------------------
// LayerNorm over h = x + agg
// ---------------------------------------------------------------------------
__global__ __launch_bounds__(256) void ln_kernel(const float* __restrict__ agg,
                                                 const float* __restrict__ x,
                                                 const float* __restrict__ gamma,
                                                 const float* __restrict__ beta,
                                                 float* __restrict__ out, int N) {
  int wave = threadIdx.x >> 6, lane = threadIdx.x & 63;
  long row = (long)blockIdx.x * 4 + wave;
  if (row >= N) return;
  int c = lane * 2;
  f32x2 av = *(const f32x2*)&agg[row * D + c];
  f32x2 xv = *(const f32x2*)&x[row * D + c];
  float h0 = av.x + xv.x, h1 = av.y + xv.y;
  float sum = h0 + h1;
  float sq = h0 * h0 + h1 * h1;
#pragma unroll
  for (int o = 32; o; o >>= 1) {
    sum += __shfl_xor(sum, o, 64);
    sq += __shfl_xor(sq, o, 64);
  }
  float mu = sum * (1.0f / 128.0f);
  float var = sq * (1.0f / 128.0f) - mu * mu;
  float rstd = rsqrtf(var + 1e-5f);
  f32x2 gv = *(const f32x2*)&gamma[c];
  f32x2 bv = *(const f32x2*)&beta[c];
  f32x2 ov;
  ov.x = (h0 - mu) * rstd * gv.x + bv.x;
  ov.y = (h1 - mu) * rstd * gv.y + bv.y;
  *(f32x2*)&out[row * D + c] = ov;
}

// ---------------------------------------------------------------------------
extern "C" void kernel_launch(void* const* d_in, const int* in_sizes, int n_in,
                              void* d_out, int out_size, void* d_ws, size_t ws_size,
                              hipStream_t stream) {
  const float* x    = (const float*)d_in[0];
  const int*   gi   = (const int*)d_in[1];
  const int*   gj   = (const int*)d_in[2];
  const float* rbf  = (const float*)d_in[3];
  const float* Wl   = (const float*)d_in[4];
  const float* bl   = (const float*)d_in[5];
  const float* W0   = (const float*)d_in[6];
  const float* b0   = (const float*)d_in[7];
  const float* W2   = (const float*)d_in[8];
  const float* b2   = (const float*)d_in[9];
  const float* gam  = (const float*)d_in[10];
  const float* bet  = (const float*)d_in[11];

  const int N = in_sizes[0] / D;  // 50000
  const int E = in_sizes[1];      // 600000

  char* ws = (char*)d_ws;
  size_t off = 0;
  float* h    = (float*)(ws + off); off += (size_t)N * D * 4;
  short* WxhB = (short*)(ws + off); off += (size_t)N * D * 2;
  int4*  edat = (int4*)(ws + off);  off += (size_t)E * 16;
  int*   cnt  = (int*)(ws + off);   off += (size_t)N * 4;
  int*   pref = (int*)(ws + off);   off += (size_t)N * 4;
  int*   woff = (int*)(ws + off);   off += (size_t)N * 4;
  int*   bsum = (int*)(ws + off);   off += 1024;
  short* Wcb  = (short*)(ws + off); off += D * D * 2;
  short* W2b  = (short*)(ws + off); off += D * D * 2;

  const int ntiles = (E + 63) / 64;     // 64 edges per tile (4 waves x 16)
  const int nb = (N + 255) / 256;

  prep_kernel<<<128 + nb + 1024, 256, 0, stream>>>(W0, W2, Wcb, W2b,
                                                   cnt, h, N, nb, (long)N * D / 4);
  hist_kernel<<<(E / 4 + 255) / 256, 256, 0, stream>>>(gi, cnt, E);
  scan_a_kernel<<<nb, 256, 0, stream>>>(cnt, pref, bsum, N);
  scan_c_kernel<<<nb, 256, 0, stream>>>(pref, bsum, woff, N);
  scatter_kernel<<<(E + 255) / 256, 256, 0, stream>>>(gi, gj, woff, edat, E);
  node_gemm_kernel<<<(N + 63) / 64, 256, 0, stream>>>(x, Wl, bl, WxhB, N);
  fused_edge_kernel<<<512, 256, 0, stream>>>(rbf, b0, b2, Wcb, W2b, WxhB,
                                             edat, h, E, ntiles);
  ln_kernel<<<(N + 3) / 4, 256, 0, stream>>>(h, x, gam, bet, (float*)d_out, N);
}

// Round 15
// 218.452 us; speedup vs baseline: 1.8697x; 1.0602x over previous
//
#include <hip/hip_runtime.h>
#include <math.h>

#define D 128

typedef __attribute__((ext_vector_type(8))) short short8_t;
typedef __attribute__((ext_vector_type(4))) float f32x4;
typedef __attribute__((ext_vector_type(2))) float f32x2;

__device__ __forceinline__ short f2bf(float f) {
  union { float f; unsigned u; } v; v.f = f;
  unsigned r = v.u + 0x7FFFu + ((v.u >> 16) & 1u);  // round-to-nearest-even
  return (short)(r >> 16);
}
__device__ __forceinline__ float bf2f(unsigned u16) {
  union { unsigned u; float f; } v; v.u = u16 << 16; return v.f;
}
// packed f32x2 -> bf16x2 (hardware, 1 instr)
__device__ __forceinline__ unsigned cvt_pk_bf16(float a, float b) {
  unsigned r;
  asm("v_cvt_pk_bf16_f32 %0, %1, %2" : "=v"(r) : "v"(a), "v"(b));
  return r;
}
typedef union { short8_t s8; unsigned u[4]; } pk8;

// ---------------------------------------------------------------------------
// prep (merged): Wc = W0@W0 -> bf16 | W2 -> bf16 | zero cnt | h = x |
//                node GEMM: WxhB = bf16(x @ Wl^T + bl)
// blocks: [0,64) Wc | [64,128) W2b | [128,128+nb) cnt | next 512: h=x |
//         rest: node_gemm (block index rebased)
// ---------------------------------------------------------------------------
__global__ __launch_bounds__(256, 2) void prep_kernel(
    const float* __restrict__ W0, const float* __restrict__ W2,
    const float* __restrict__ x, const float* __restrict__ Wl,
    const float* __restrict__ bl,
    short* __restrict__ Wcb, short* __restrict__ W2b,
    int* __restrict__ count, float* __restrict__ h, short* __restrict__ WxhB,
    int N, int nb, long h4) {
  __shared__ short Wl_s[D * D];
  int b = blockIdx.x, t = threadIdx.x;
  if (b < 64) {
    int idx = b * 256 + t;
    int r = idx >> 7, c = idx & 127;
    float s = 0.f;
    for (int k = 0; k < D; ++k) s += W0[r * D + k] * W0[k * D + c];
    Wcb[idx] = f2bf(s);
    return;
  } else if (b < 128) {
    int idx = (b - 64) * 256 + t;
    W2b[idx] = f2bf(W2[idx]);
    return;
  } else if (b < 128 + nb) {
    int idx = (b - 128) * 256 + t;
    if (idx < N) count[idx] = 0;
    return;
  } else if (b < 128 + nb + 512) {
    long i = (long)(b - 128 - nb) * 256 + t;
    for (; i < h4; i += 512L * 256) ((f32x4*)h)[i] = ((const f32x4*)x)[i];
    return;
  }
  // ---- node GEMM ----
  const int bg = b - (128 + nb + 512);
  const int lane = t & 63, wave = t >> 6;
  const int q = lane & 15, g = lane >> 4;

  for (int it = 0; it < 8; ++it) {
    int eoff = (it * 256 + t) * 8;
    int row = eoff >> 7, col = eoff & 127;
    int scol = col ^ ((row & 7) << 3);
    f32x4 v0 = *(const f32x4*)&Wl[eoff];
    f32x4 v1 = *(const f32x4*)&Wl[eoff + 4];
    pk8 tt;
    tt.u[0] = cvt_pk_bf16(v0.x, v0.y); tt.u[1] = cvt_pk_bf16(v0.z, v0.w);
    tt.u[2] = cvt_pk_bf16(v1.x, v1.y); tt.u[3] = cvt_pk_bf16(v1.z, v1.w);
    *(short8_t*)&Wl_s[row * D + scol] = tt.s8;
  }

  const int rbase = bg * 64 + wave * 16;
  int arow = rbase + q; if (arow > N - 1) arow = N - 1;
  short8_t a[4];
  const float* src = x + (size_t)arow * D;
#pragma unroll
  for (int c = 0; c < 4; ++c) {
    int kb = c * 32 + g * 8;
    f32x4 v0 = *(const f32x4*)(src + kb);
    f32x4 v1 = *(const f32x4*)(src + kb + 4);
    pk8 tt;
    tt.u[0] = cvt_pk_bf16(v0.x, v0.y); tt.u[1] = cvt_pk_bf16(v0.z, v0.w);
    tt.u[2] = cvt_pk_bf16(v1.x, v1.y); tt.u[3] = cvt_pk_bf16(v1.z, v1.w);
    a[c] = tt.s8;
  }

  __syncthreads();

  f32x4 acc[8];
#pragma unroll
  for (int n = 0; n < 8; ++n) acc[n] = f32x4{0.f, 0.f, 0.f, 0.f};
#pragma unroll
  for (int n = 0; n < 8; ++n) {
    int row = n * 16 + q;
    int sw = (row & 7) << 3;
#pragma unroll
    for (int c = 0; c < 4; ++c) {
      int col = (c * 32 + g * 8) ^ sw;
      short8_t bb = *(const short8_t*)&Wl_s[row * D + col];
      acc[n] = __builtin_amdgcn_mfma_f32_16x16x32_bf16(a[c], bb, acc[n], 0, 0, 0);
    }
  }

#pragma unroll
  for (int n = 0; n < 8; ++n) {
    int col = n * 16 + q;
    float bias = bl[col];
#pragma unroll
    for (int r = 0; r < 4; ++r) {
      int orow = rbase + g * 4 + r;
      if (orow < N) WxhB[(size_t)orow * D + col] = f2bf(acc[n][r] + bias);
    }
  }
}

// ---------------------------------------------------------------------------
__global__ void hist_kernel(const int* __restrict__ gi, int* __restrict__ count, int E) {
  int t = blockIdx.x * 256 + threadIdx.x;
  int base = t * 4;
  if (base + 3 < E) {
    int4 v = *(const int4*)(gi + base);
    atomicAdd(&count[v.x], 1);
    atomicAdd(&count[v.y], 1);
    atomicAdd(&count[v.z], 1);
    atomicAdd(&count[v.w], 1);
  } else {
    for (int k = base; k < E; ++k) atomicAdd(&count[gi[k]], 1);
  }
}

// ---------------------------------------------------------------------------
__global__ __launch_bounds__(256) void scan_a_kernel(const int* __restrict__ count,
                                                     int* __restrict__ pref,
                                                     int* __restrict__ bsum, int N) {
  __shared__ int ws[4];
  const int tid = threadIdx.x, lane = tid & 63, wave = tid >> 6;
  int i = blockIdx.x * 256 + tid;
  int c = (i < N) ? count[i] : 0;
  int v = c;
#pragma unroll
  for (int o = 1; o < 64; o <<= 1) {
    int u = __shfl_up(v, o, 64);
    if (lane >= o) v += u;
  }
  if (lane == 63) ws[wave] = v;
  __syncthreads();
  int wp = 0;
  for (int w = 0; w < wave; ++w) wp += ws[w];
  if (i < N) pref[i] = wp + v - c;
  if (tid == 255) bsum[blockIdx.x] = wp + v;
}

__global__ __launch_bounds__(256) void scan_c_kernel(const int* __restrict__ pref,
                                                     const int* __restrict__ bsum,
                                                     int* __restrict__ woff, int N) {
  __shared__ int base_s;
  const int tid = threadIdx.x, lane = tid & 63;
  if (tid < 64) {
    int p = 0;
    for (int k = lane; k < blockIdx.x; k += 64) p += bsum[k];
#pragma unroll
    for (int o = 32; o; o >>= 1) p += __shfl_xor(p, o, 64);
    if (lane == 0) base_s = p;
  }
  __syncthreads();
  int i = blockIdx.x * 256 + tid;
  if (i < N) woff[i] = pref[i] + base_s;
}

// ---------------------------------------------------------------------------
__global__ void scatter_kernel(const int* __restrict__ gi, const int* __restrict__ gj,
                               int* __restrict__ woff, int4* __restrict__ edata, int E) {
  int e = blockIdx.x * 256 + threadIdx.x;
  if (e < E) {
    int i = gi[e];
    int pos = atomicAdd(&woff[i], 1);
    int4 ed; ed.x = e; ed.y = gj[e]; ed.z = i; ed.w = 0;
    edata[pos] = ed;
  }
}

// ---------------------------------------------------------------------------
// fused edge kernel — VERBATIM r12 (known-good 231.6 µs, absmax 0.03125):
// both weights in LDS (80 KB, 2 blocks/CU), edata 3-deep + rbf/Wxh 1-deep
// prefetch, packed cvt conversions, rcp-silu, LDS-transpose + coalesced
// segmented reduce with f32 atomics.
// ---------------------------------------------------------------------------
__global__ __launch_bounds__(256, 2) void fused_edge_kernel(
    const float* __restrict__ rbf, const float* __restrict__ b0v,
    const float* __restrict__ b2v, const short* __restrict__ Wcb,
    const short* __restrict__ W2b, const short* __restrict__ WxhB,
    const int4* __restrict__ edata, float* __restrict__ h, int E, int ntiles) {
  __shared__ short Wc_s[D * D];
  __shared__ short W2_s[D * D];
  __shared__ short m_s[4][16 * D];

  const int tid = threadIdx.x;
  const int lane = tid & 63, wave = tid >> 6;
  const int q = lane & 15, g = lane >> 4;

  for (int it = 0; it < 8; ++it) {
    int eoff = (it * 256 + tid) * 8;
    int row = eoff >> 7, col = eoff & 127;
    int scol = col ^ ((row & 7) << 3);
    *(short8_t*)&Wc_s[row * D + scol] = *(const short8_t*)&Wcb[eoff];
    *(short8_t*)&W2_s[row * D + scol] = *(const short8_t*)&W2b[eoff];
  }

  float b0r[8], b2r[8];
#pragma unroll
  for (int n = 0; n < 8; ++n) { b0r[n] = b0v[n * 16 + q]; b2r[n] = b2v[n * 16 + q]; }

  __syncthreads();

  short* ms = &m_s[wave][0];
  const int stride = gridDim.x;

  int tile = blockIdx.x;
  if (tile >= ntiles) return;

#define EQOF(t) ({ int tc_ = (t) < ntiles ? (t) : ntiles - 1;                  \
                   int e_ = tc_ * 64 + wave * 16 + q;                          \
                   e_ < E ? e_ : E - 1; })

  // prologue: edata 3-deep, rbf + Wxh 1-deep (for tile t)
  int4 ed0 = edata[EQOF(tile)];
  int4 ed1 = edata[EQOF(tile + stride)];
  int4 ed2 = edata[EQOF(tile + 2 * stride)];
  f32x4 rb[8];
  {
    const float* src = rbf + (size_t)ed0.x * D;
#pragma unroll
    for (int c = 0; c < 4; ++c) {
      rb[c * 2]     = *(const f32x4*)(src + c * 32 + g * 8);
      rb[c * 2 + 1] = *(const f32x4*)(src + c * 32 + g * 8 + 4);
    }
  }
  unsigned wv0[16];
#pragma unroll
  for (int r = 0; r < 16; ++r) {
    int jr = __shfl(ed0.y, r, 64);
    wv0[r] = *(const unsigned*)&WxhB[(size_t)jr * D + lane * 2];
  }

  while (true) {
    const bool hnext = (tile + stride) < ntiles;

    // consume rb(t) -> A fragments (packed hw conversion)
    short8_t a[4];
#pragma unroll
    for (int c = 0; c < 4; ++c) {
      f32x4 v0 = rb[c * 2], v1 = rb[c * 2 + 1];
      pk8 t;
      t.u[0] = cvt_pk_bf16(v0.x, v0.y); t.u[1] = cvt_pk_bf16(v0.z, v0.w);
      t.u[2] = cvt_pk_bf16(v1.x, v1.y); t.u[3] = cvt_pk_bf16(v1.z, v1.w);
      a[c] = t.s8;
    }

    // issue next-tile loads (edata 3 ahead, rbf/Wxh 1 ahead)
    int4 ed3 = edata[EQOF(tile + 3 * stride)];
    {
      const float* src = rbf + (size_t)ed1.x * D;
#pragma unroll
      for (int c = 0; c < 4; ++c) {
        rb[c * 2]     = *(const f32x4*)(src + c * 32 + g * 8);
        rb[c * 2 + 1] = *(const f32x4*)(src + c * 32 + g * 8 + 4);
      }
    }
    unsigned wv1[16];
#pragma unroll
    for (int r = 0; r < 16; ++r) {
      int jr = __shfl(ed1.y, r, 64);
      wv1[r] = *(const unsigned*)&WxhB[(size_t)jr * D + lane * 2];
    }

    // GEMM1: u = rbf @ Wc^T (B from LDS)
    f32x4 acc[8];
#pragma unroll
    for (int n = 0; n < 8; ++n) acc[n] = f32x4{0.f, 0.f, 0.f, 0.f};
#pragma unroll
    for (int n = 0; n < 8; ++n) {
      int row = n * 16 + q;
      int sw = (row & 7) << 3;
#pragma unroll
      for (int c = 0; c < 4; ++c) {
        int col = (c * 32 + g * 8) ^ sw;
        short8_t b = *(const short8_t*)&Wc_s[row * D + col];
        acc[n] = __builtin_amdgcn_mfma_f32_16x16x32_bf16(a[c], b, acc[n], 0, 0, 0);
      }
    }

    // silu(u + b0) -> wave-private LDS tile (bf16, swizzled)
#pragma unroll
    for (int n = 0; n < 8; ++n) {
      int col = n * 16 + q;
      float s[4];
#pragma unroll
      for (int r = 0; r < 4; ++r) {
        float u = acc[n][r] + b0r[n];
        s[r] = u * __builtin_amdgcn_rcpf(1.0f + __expf(-u));
      }
      unsigned p01 = cvt_pk_bf16(s[0], s[1]);
      unsigned p23 = cvt_pk_bf16(s[2], s[3]);
      int r0 = g * 4;
      ms[(r0 + 0) * D + (col ^ (((r0 + 0) & 7) << 3))] = (short)p01;
      ms[(r0 + 1) * D + (col ^ (((r0 + 1) & 7) << 3))] = (short)(p01 >> 16);
      ms[(r0 + 2) * D + (col ^ (((r0 + 2) & 7) << 3))] = (short)p23;
      ms[(r0 + 3) * D + (col ^ (((r0 + 3) & 7) << 3))] = (short)(p23 >> 16);
    }

    // transposed A fragments
    short8_t a2[4];
    {
      int sw = (q & 7) << 3;
#pragma unroll
      for (int c = 0; c < 4; ++c) {
        int col = (c * 32 + g * 8) ^ sw;
        a2[c] = *(const short8_t*)&ms[q * D + col];
      }
    }

    // GEMM2: m = silu(u) @ W2^T (reuse acc; B from LDS)
#pragma unroll
    for (int n = 0; n < 8; ++n) acc[n] = f32x4{0.f, 0.f, 0.f, 0.f};
#pragma unroll
    for (int n = 0; n < 8; ++n) {
      int row = n * 16 + q;
      int sw = (row & 7) << 3;
#pragma unroll
      for (int c = 0; c < 4; ++c) {
        int col = (c * 32 + g * 8) ^ sw;
        short8_t b = *(const short8_t*)&W2_s[row * D + col];
        acc[n] = __builtin_amdgcn_mfma_f32_16x16x32_bf16(a2[c], b, acc[n], 0, 0, 0);
      }
    }

    // m + b2 -> bf16 back into the wave tile (packed cvt)
#pragma unroll
    for (int n = 0; n < 8; ++n) {
      int col = n * 16 + q;
      unsigned p01 = cvt_pk_bf16(acc[n][0] + b2r[n], acc[n][1] + b2r[n]);
      unsigned p23 = cvt_pk_bf16(acc[n][2] + b2r[n], acc[n][3] + b2r[n]);
      int r0 = g * 4;
      ms[(r0 + 0) * D + (col ^ (((r0 + 0) & 7) << 3))] = (short)p01;
      ms[(r0 + 1) * D + (col ^ (((r0 + 1) & 7) << 3))] = (short)(p01 >> 16);
      ms[(r0 + 2) * D + (col ^ (((r0 + 2) & 7) << 3))] = (short)p23;
      ms[(r0 + 3) * D + (col ^ (((r0 + 3) & 7) << 3))] = (short)(p23 >> 16);
    }

    // segmented reduce with wv0/ed0 (rows sorted by destination i)
    const int eb = tile * 64 + wave * 16;
    int nv = E - eb; if (nv > 16) nv = 16;
    float a0 = 0.f, a1 = 0.f;
    int cur = -1;
#pragma unroll
    for (int r = 0; r < 16; ++r) {
      if (r < nv) {
        int ir = __shfl(ed0.z, r, 64);
        if (ir != cur) {
          if (cur >= 0) {
            float* dst = &h[(size_t)cur * D + lane * 2];
            __hip_atomic_fetch_add(dst, a0, __ATOMIC_RELAXED, __HIP_MEMORY_SCOPE_AGENT);
            __hip_atomic_fetch_add(dst + 1, a1, __ATOMIC_RELAXED, __HIP_MEMORY_SCOPE_AGENT);
            a0 = a1 = 0.f;
          }
          cur = ir;
        }
        unsigned mv = *(const unsigned*)&ms[r * D + ((lane * 2) ^ ((r & 7) << 3))];
        a0 += bf2f(mv & 0xffffu) * bf2f(wv0[r] & 0xffffu);
        a1 += bf2f(mv >> 16) * bf2f(wv0[r] >> 16);
      }
    }
    if (cur >= 0) {
      float* dst = &h[(size_t)cur * D + lane * 2];
      __hip_atomic_fetch_add(dst, a0, __ATOMIC_RELAXED, __HIP_MEMORY_SCOPE_AGENT);
      __hip_atomic_fetch_add(dst + 1, a1, __ATOMIC_RELAXED, __HIP_MEMORY_SCOPE_AGENT);
    }

    if (!hnext) break;
    tile += stride;
    ed0 = ed1; ed1 = ed2; ed2 = ed3;
#pragma unroll
    for (int r = 0; r < 16; ++r) wv0[r] = wv1[r];
  }
#undef EQOF
}

// ---------------------------------------------------------------------------
// LayerNorm over h (h = x + agg already)
// ---------------------------------------------------------------------------
__global__ __launch_bounds__(256) void ln_kernel(const float* __restrict__ hbuf,
                                                 const float* __restrict__ gamma,
                                                 const float* __restrict__ beta,
                                                 float* __restrict__ out, int N) {
  int wave = threadIdx.x >> 6, lane = threadIdx.x & 63;
  long row = (long)blockIdx.x * 4 + wave;
  if (row >= N) return;
  int c = lane * 2;
  f32x2 v = *(const f32x2*)&hbuf[row * D + c];
  float h0 = v.x, h1 = v.y;
  float sum = h0 + h1;
  float sq = h0 * h0 + h1 * h1;
#pragma unroll
  for (int o = 32; o; o >>= 1) {
    sum += __shfl_xor(sum, o, 64);
    sq += __shfl_xor(sq, o, 64);
  }
  float mu = sum * (1.0f / 128.0f);
  float var = sq * (1.0f / 128.0f) - mu * mu;
  float rstd = rsqrtf(var + 1e-5f);
  f32x2 gv = *(const f32x2*)&gamma[c];
  f32x2 bv = *(const f32x2*)&beta[c];
  f32x2 ov;
  ov.x = (h0 - mu) * rstd * gv.x + bv.x;
  ov.y = (h1 - mu) * rstd * gv.y + bv.y;
  *(f32x2*)&out[row * D + c] = ov;
}

// ---------------------------------------------------------------------------
extern "C" void kernel_launch(void* const* d_in, const int* in_sizes, int n_in,
                              void* d_out, int out_size, void* d_ws, size_t ws_size,
                              hipStream_t stream) {
  const float* x    = (const float*)d_in[0];
  const int*   gi   = (const int*)d_in[1];
  const int*   gj   = (const int*)d_in[2];
  const float* rbf  = (const float*)d_in[3];
  const float* Wl   = (const float*)d_in[4];
  const float* bl   = (const float*)d_in[5];
  const float* W0   = (const float*)d_in[6];
  const float* b0   = (const float*)d_in[7];
  const float* W2   = (const float*)d_in[8];
  const float* b2   = (const float*)d_in[9];
  const float* gam  = (const float*)d_in[10];
  const float* bet  = (const float*)d_in[11];

  const int N = in_sizes[0] / D;  // 50000
  const int E = in_sizes[1];      // 600000

  char* ws = (char*)d_ws;
  size_t off = 0;
  float* h    = (float*)(ws + off); off += (size_t)N * D * 4;
  short* WxhB = (short*)(ws + off); off += (size_t)N * D * 2;
  int4*  edat = (int4*)(ws + off);  off += (size_t)E * 16;
  int*   cnt  = (int*)(ws + off);   off += (size_t)N * 4;
  int*   pref = (int*)(ws + off);   off += (size_t)N * 4;
  int*   woff = (int*)(ws + off);   off += (size_t)N * 4;
  int*   bsum = (int*)(ws + off);   off += 1024;
  short* Wcb  = (short*)(ws + off); off += D * D * 2;
  short* W2b  = (short*)(ws + off); off += D * D * 2;

  const int ntiles = (E + 63) / 64;     // 64 edges per tile (4 waves x 16)
  const int nb = (N + 255) / 256;       // 196
  const int ngemm = (N + 63) / 64;      // 782

  prep_kernel<<<128 + nb + 512 + ngemm, 256, 0, stream>>>(
      W0, W2, x, Wl, bl, Wcb, W2b, cnt, h, WxhB, N, nb, (long)N * D / 4);
  hist_kernel<<<(E / 4 + 255) / 256, 256, 0, stream>>>(gi, cnt, E);
  scan_a_kernel<<<nb, 256, 0, stream>>>(cnt, pref, bsum, N);
  scan_c_kernel<<<nb, 256, 0, stream>>>(pref, bsum, woff, N);
  scatter_kernel<<<(E + 255) / 256, 256, 0, stream>>>(gi, gj, woff, edat, E);
  fused_edge_kernel<<<512, 256, 0, stream>>>(rbf, b0, b2, Wcb, W2b, WxhB,
                                             edat, h, E, ntiles);
  ln_kernel<<<(N + 3) / 4, 256, 0, stream>>>(h, gam, bet, (float*)d_out, N);
}

// Round 16
// 218.271 us; speedup vs baseline: 1.8712x; 1.0008x over previous
//
#include <hip/hip_runtime.h>
#include <math.h>

#define D 128

typedef __attribute__((ext_vector_type(8))) short short8_t;
typedef __attribute__((ext_vector_type(4))) float f32x4;
typedef __attribute__((ext_vector_type(2))) float f32x2;

__device__ __forceinline__ short f2bf(float f) {
  union { float f; unsigned u; } v; v.f = f;
  unsigned r = v.u + 0x7FFFu + ((v.u >> 16) & 1u);  // round-to-nearest-even
  return (short)(r >> 16);
}
__device__ __forceinline__ float bf2f(unsigned u16) {
  union { unsigned u; float f; } v; v.u = u16 << 16; return v.f;
}
// packed f32x2 -> bf16x2 (hardware, 1 instr)
__device__ __forceinline__ unsigned cvt_pk_bf16(float a, float b) {
  unsigned r;
  asm("v_cvt_pk_bf16_f32 %0, %1, %2" : "=v"(r) : "v"(a), "v"(b));
  return r;
}
typedef union { short8_t s8; unsigned u[4]; } pk8;

// ---------------------------------------------------------------------------
// prep (merged): Wc = W0@W0 -> bf16 | W2 -> bf16 | zero cnt | h = x |
//                node GEMM: WxhB = bf16(x @ Wl^T + bl)
// ---------------------------------------------------------------------------
__global__ __launch_bounds__(256, 2) void prep_kernel(
    const float* __restrict__ W0, const float* __restrict__ W2,
    const float* __restrict__ x, const float* __restrict__ Wl,
    const float* __restrict__ bl,
    short* __restrict__ Wcb, short* __restrict__ W2b,
    int* __restrict__ count, float* __restrict__ h, short* __restrict__ WxhB,
    int N, int nb, long h4) {
  __shared__ short Wl_s[D * D];
  int b = blockIdx.x, t = threadIdx.x;
  if (b < 64) {
    int idx = b * 256 + t;
    int r = idx >> 7, c = idx & 127;
    float s = 0.f;
    for (int k = 0; k < D; ++k) s += W0[r * D + k] * W0[k * D + c];
    Wcb[idx] = f2bf(s);
    return;
  } else if (b < 128) {
    int idx = (b - 64) * 256 + t;
    W2b[idx] = f2bf(W2[idx]);
    return;
  } else if (b < 128 + nb) {
    int idx = (b - 128) * 256 + t;
    if (idx < N) count[idx] = 0;
    return;
  } else if (b < 128 + nb + 512) {
    long i = (long)(b - 128 - nb) * 256 + t;
    for (; i < h4; i += 512L * 256) ((f32x4*)h)[i] = ((const f32x4*)x)[i];
    return;
  }
  // ---- node GEMM ----
  const int bg = b - (128 + nb + 512);
  const int lane = t & 63, wave = t >> 6;
  const int q = lane & 15, g = lane >> 4;

  for (int it = 0; it < 8; ++it) {
    int eoff = (it * 256 + t) * 8;
    int row = eoff >> 7, col = eoff & 127;
    int scol = col ^ ((row & 7) << 3);
    f32x4 v0 = *(const f32x4*)&Wl[eoff];
    f32x4 v1 = *(const f32x4*)&Wl[eoff + 4];
    pk8 tt;
    tt.u[0] = cvt_pk_bf16(v0.x, v0.y); tt.u[1] = cvt_pk_bf16(v0.z, v0.w);
    tt.u[2] = cvt_pk_bf16(v1.x, v1.y); tt.u[3] = cvt_pk_bf16(v1.z, v1.w);
    *(short8_t*)&Wl_s[row * D + scol] = tt.s8;
  }

  const int rbase = bg * 64 + wave * 16;
  int arow = rbase + q; if (arow > N - 1) arow = N - 1;
  short8_t a[4];
  const float* src = x + (size_t)arow * D;
#pragma unroll
  for (int c = 0; c < 4; ++c) {
    int kb = c * 32 + g * 8;
    f32x4 v0 = *(const f32x4*)(src + kb);
    f32x4 v1 = *(const f32x4*)(src + kb + 4);
    pk8 tt;
    tt.u[0] = cvt_pk_bf16(v0.x, v0.y); tt.u[1] = cvt_pk_bf16(v0.z, v0.w);
    tt.u[2] = cvt_pk_bf16(v1.x, v1.y); tt.u[3] = cvt_pk_bf16(v1.z, v1.w);
    a[c] = tt.s8;
  }

  __syncthreads();

  f32x4 acc[8];
#pragma unroll
  for (int n = 0; n < 8; ++n) acc[n] = f32x4{0.f, 0.f, 0.f, 0.f};
#pragma unroll
  for (int n = 0; n < 8; ++n) {
    int row = n * 16 + q;
    int sw = (row & 7) << 3;
#pragma unroll
    for (int c = 0; c < 4; ++c) {
      int col = (c * 32 + g * 8) ^ sw;
      short8_t bb = *(const short8_t*)&Wl_s[row * D + col];
      acc[n] = __builtin_amdgcn_mfma_f32_16x16x32_bf16(a[c], bb, acc[n], 0, 0, 0);
    }
  }

#pragma unroll
  for (int n = 0; n < 8; ++n) {
    int col = n * 16 + q;
    float bias = bl[col];
#pragma unroll
    for (int r = 0; r < 4; ++r) {
      int orow = rbase + g * 4 + r;
      if (orow < N) WxhB[(size_t)orow * D + col] = f2bf(acc[n][r] + bias);
    }
  }
}

// ---------------------------------------------------------------------------
__global__ void hist_kernel(const int* __restrict__ gi, int* __restrict__ count, int E) {
  int t = blockIdx.x * 256 + threadIdx.x;
  int base = t * 4;
  if (base + 3 < E) {
    int4 v = *(const int4*)(gi + base);
    atomicAdd(&count[v.x], 1);
    atomicAdd(&count[v.y], 1);
    atomicAdd(&count[v.z], 1);
    atomicAdd(&count[v.w], 1);
  } else {
    for (int k = base; k < E; ++k) atomicAdd(&count[gi[k]], 1);
  }
}

// ---------------------------------------------------------------------------
__global__ __launch_bounds__(256) void scan_a_kernel(const int* __restrict__ count,
                                                     int* __restrict__ pref,
                                                     int* __restrict__ bsum, int N) {
  __shared__ int ws[4];
  const int tid = threadIdx.x, lane = tid & 63, wave = tid >> 6;
  int i = blockIdx.x * 256 + tid;
  int c = (i < N) ? count[i] : 0;
  int v = c;
#pragma unroll
  for (int o = 1; o < 64; o <<= 1) {
    int u = __shfl_up(v, o, 64);
    if (lane >= o) v += u;
  }
  if (lane == 63) ws[wave] = v;
  __syncthreads();
  int wp = 0;
  for (int w = 0; w < wave; ++w) wp += ws[w];
  if (i < N) pref[i] = wp + v - c;
  if (tid == 255) bsum[blockIdx.x] = wp + v;
}

__global__ __launch_bounds__(256) void scan_c_kernel(const int* __restrict__ pref,
                                                     const int* __restrict__ bsum,
                                                     int* __restrict__ woff, int N) {
  __shared__ int base_s;
  const int tid = threadIdx.x, lane = tid & 63;
  if (tid < 64) {
    int p = 0;
    for (int k = lane; k < blockIdx.x; k += 64) p += bsum[k];
#pragma unroll
    for (int o = 32; o; o >>= 1) p += __shfl_xor(p, o, 64);
    if (lane == 0) base_s = p;
  }
  __syncthreads();
  int i = blockIdx.x * 256 + tid;
  if (i < N) woff[i] = pref[i] + base_s;
}

// ---------------------------------------------------------------------------
__global__ void scatter_kernel(const int* __restrict__ gi, const int* __restrict__ gj,
                               int* __restrict__ woff, int4* __restrict__ edata, int E) {
  int e = blockIdx.x * 256 + threadIdx.x;
  if (e < E) {
    int i = gi[e];
    int pos = atomicAdd(&woff[i], 1);
    int4 ed; ed.x = e; ed.y = gj[e]; ed.z = i; ed.w = 0;
    edata[pos] = ed;
  }
}

// ---------------------------------------------------------------------------
// fused edge kernel v11 = r15/r12 structure with ONE change: Wc/W2 stored in
// LDS in FRAGMENT-MAJOR layout — each MFMA B-fragment (8 shorts) contiguous
// at ((n*4+c)*16+q)*4+g. Per (n,c) the wave reads 64 distinct consecutive
// 16B slots of a 1KB block: stride-1, zero bank conflicts (was ~8-way: the
// row term row*256B ≡ 0 mod bank cycle contributed nothing). B-read addrs
// become base + compile-time immediate — kills per-read address VALU too.
// Same LDS size (80KB, 2 blocks/CU). Everything else verbatim r15.
// ---------------------------------------------------------------------------
__global__ __launch_bounds__(256, 2) void fused_edge_kernel(
    const float* __restrict__ rbf, const float* __restrict__ b0v,
    const float* __restrict__ b2v, const short* __restrict__ Wcb,
    const short* __restrict__ W2b, const short* __restrict__ WxhB,
    const int4* __restrict__ edata, float* __restrict__ h, int E, int ntiles) {
  __shared__ short Wc_s[D * D];
  __shared__ short W2_s[D * D];
  __shared__ short m_s[4][16 * D];

  const int tid = threadIdx.x;
  const int lane = tid & 63, wave = tid >> 6;
  const int q = lane & 15, g = lane >> 4;

  // stage weights fragment-major: lin = ((n*4+c)*16+q)*4+g, 8 shorts each
  for (int it = 0; it < 8; ++it) {
    int lin = it * 256 + tid;          // 0..2047
    int gg = lin & 3;
    int qq = (lin >> 2) & 15;
    int cc = (lin >> 6) & 3;
    int nn = lin >> 8;
    int src = (nn * 16 + qq) * D + cc * 32 + gg * 8;
    *(short8_t*)&Wc_s[lin * 8] = *(const short8_t*)&Wcb[src];
    *(short8_t*)&W2_s[lin * 8] = *(const short8_t*)&W2b[src];
  }

  float b0r[8], b2r[8];
#pragma unroll
  for (int n = 0; n < 8; ++n) { b0r[n] = b0v[n * 16 + q]; b2r[n] = b2v[n * 16 + q]; }

  __syncthreads();

  short* ms = &m_s[wave][0];
  const int fbase = (q * 4 + g) * 8;   // per-lane fragment base (shorts)
  const int stride = gridDim.x;

  int tile = blockIdx.x;
  if (tile >= ntiles) return;

#define EQOF(t) ({ int tc_ = (t) < ntiles ? (t) : ntiles - 1;                  \
                   int e_ = tc_ * 64 + wave * 16 + q;                          \
                   e_ < E ? e_ : E - 1; })

  // prologue: edata 3-deep, rbf + Wxh 1-deep (for tile t)
  int4 ed0 = edata[EQOF(tile)];
  int4 ed1 = edata[EQOF(tile + stride)];
  int4 ed2 = edata[EQOF(tile + 2 * stride)];
  f32x4 rb[8];
  {
    const float* src = rbf + (size_t)ed0.x * D;
#pragma unroll
    for (int c = 0; c < 4; ++c) {
      rb[c * 2]     = *(const f32x4*)(src + c * 32 + g * 8);
      rb[c * 2 + 1] = *(const f32x4*)(src + c * 32 + g * 8 + 4);
    }
  }
  unsigned wv0[16];
#pragma unroll
  for (int r = 0; r < 16; ++r) {
    int jr = __shfl(ed0.y, r, 64);
    wv0[r] = *(const unsigned*)&WxhB[(size_t)jr * D + lane * 2];
  }

  while (true) {
    const bool hnext = (tile + stride) < ntiles;

    // consume rb(t) -> A fragments (packed hw conversion)
    short8_t a[4];
#pragma unroll
    for (int c = 0; c < 4; ++c) {
      f32x4 v0 = rb[c * 2], v1 = rb[c * 2 + 1];
      pk8 t;
      t.u[0] = cvt_pk_bf16(v0.x, v0.y); t.u[1] = cvt_pk_bf16(v0.z, v0.w);
      t.u[2] = cvt_pk_bf16(v1.x, v1.y); t.u[3] = cvt_pk_bf16(v1.z, v1.w);
      a[c] = t.s8;
    }

    // issue next-tile loads (edata 3 ahead, rbf/Wxh 1 ahead)
    int4 ed3 = edata[EQOF(tile + 3 * stride)];
    {
      const float* src = rbf + (size_t)ed1.x * D;
#pragma unroll
      for (int c = 0; c < 4; ++c) {
        rb[c * 2]     = *(const f32x4*)(src + c * 32 + g * 8);
        rb[c * 2 + 1] = *(const f32x4*)(src + c * 32 + g * 8 + 4);
      }
    }
    unsigned wv1[16];
#pragma unroll
    for (int r = 0; r < 16; ++r) {
      int jr = __shfl(ed1.y, r, 64);
      wv1[r] = *(const unsigned*)&WxhB[(size_t)jr * D + lane * 2];
    }

    // GEMM1: u = rbf @ Wc^T (B fragment-major from LDS, conflict-free)
    f32x4 acc[8];
#pragma unroll
    for (int n = 0; n < 8; ++n) acc[n] = f32x4{0.f, 0.f, 0.f, 0.f};
#pragma unroll
    for (int n = 0; n < 8; ++n) {
#pragma unroll
      for (int c = 0; c < 4; ++c) {
        short8_t b = *(const short8_t*)&Wc_s[(n * 2048 + c * 512) + fbase];
        acc[n] = __builtin_amdgcn_mfma_f32_16x16x32_bf16(a[c], b, acc[n], 0, 0, 0);
      }
    }

    // silu(u + b0) -> wave-private LDS tile (bf16, swizzled)
#pragma unroll
    for (int n = 0; n < 8; ++n) {
      int col = n * 16 + q;
      float s[4];
#pragma unroll
      for (int r = 0; r < 4; ++r) {
        float u = acc[n][r] + b0r[n];
        s[r] = u * __builtin_amdgcn_rcpf(1.0f + __expf(-u));
      }
      unsigned p01 = cvt_pk_bf16(s[0], s[1]);
      unsigned p23 = cvt_pk_bf16(s[2], s[3]);
      int r0 = g * 4;
      ms[(r0 + 0) * D + (col ^ (((r0 + 0) & 7) << 3))] = (short)p01;
      ms[(r0 + 1) * D + (col ^ (((r0 + 1) & 7) << 3))] = (short)(p01 >> 16);
      ms[(r0 + 2) * D + (col ^ (((r0 + 2) & 7) << 3))] = (short)p23;
      ms[(r0 + 3) * D + (col ^ (((r0 + 3) & 7) << 3))] = (short)(p23 >> 16);
    }

    // transposed A fragments
    short8_t a2[4];
    {
      int sw = (q & 7) << 3;
#pragma unroll
      for (int c = 0; c < 4; ++c) {
        int col = (c * 32 + g * 8) ^ sw;
        a2[c] = *(const short8_t*)&ms[q * D + col];
      }
    }

    // GEMM2: m = silu(u) @ W2^T (B fragment-major from LDS, conflict-free)
#pragma unroll
    for (int n = 0; n < 8; ++n) acc[n] = f32x4{0.f, 0.f, 0.f, 0.f};
#pragma unroll
    for (int n = 0; n < 8; ++n) {
#pragma unroll
      for (int c = 0; c < 4; ++c) {
        short8_t b = *(const short8_t*)&W2_s[(n * 2048 + c * 512) + fbase];
        acc[n] = __builtin_amdgcn_mfma_f32_16x16x32_bf16(a2[c], b, acc[n], 0, 0, 0);
      }
    }

    // m + b2 -> bf16 back into the wave tile (packed cvt)
#pragma unroll
    for (int n = 0; n < 8; ++n) {
      int col = n * 16 + q;
      unsigned p01 = cvt_pk_bf16(acc[n][0] + b2r[n], acc[n][1] + b2r[n]);
      unsigned p23 = cvt_pk_bf16(acc[n][2] + b2r[n], acc[n][3] + b2r[n]);
      int r0 = g * 4;
      ms[(r0 + 0) * D + (col ^ (((r0 + 0) & 7) << 3))] = (short)p01;
      ms[(r0 + 1) * D + (col ^ (((r0 + 1) & 7) << 3))] = (short)(p01 >> 16);
      ms[(r0 + 2) * D + (col ^ (((r0 + 2) & 7) << 3))] = (short)p23;
      ms[(r0 + 3) * D + (col ^ (((r0 + 3) & 7) << 3))] = (short)(p23 >> 16);
    }

    // segmented reduce with wv0/ed0 (rows sorted by destination i)
    const int eb = tile * 64 + wave * 16;
    int nv = E - eb; if (nv > 16) nv = 16;
    float a0 = 0.f, a1 = 0.f;
    int cur = -1;
#pragma unroll
    for (int r = 0; r < 16; ++r) {
      if (r < nv) {
        int ir = __shfl(ed0.z, r, 64);
        if (ir != cur) {
          if (cur >= 0) {
            float* dst = &h[(size_t)cur * D + lane * 2];
            __hip_atomic_fetch_add(dst, a0, __ATOMIC_RELAXED, __HIP_MEMORY_SCOPE_AGENT);
            __hip_atomic_fetch_add(dst + 1, a1, __ATOMIC_RELAXED, __HIP_MEMORY_SCOPE_AGENT);
            a0 = a1 = 0.f;
          }
          cur = ir;
        }
        unsigned mv = *(const unsigned*)&ms[r * D + ((lane * 2) ^ ((r & 7) << 3))];
        a0 += bf2f(mv & 0xffffu) * bf2f(wv0[r] & 0xffffu);
        a1 += bf2f(mv >> 16) * bf2f(wv0[r] >> 16);
      }
    }
    if (cur >= 0) {
      float* dst = &h[(size_t)cur * D + lane * 2];
      __hip_atomic_fetch_add(dst, a0, __ATOMIC_RELAXED, __HIP_MEMORY_SCOPE_AGENT);
      __hip_atomic_fetch_add(dst + 1, a1, __ATOMIC_RELAXED, __HIP_MEMORY_SCOPE_AGENT);
    }

    if (!hnext) break;
    tile += stride;
    ed0 = ed1; ed1 = ed2; ed2 = ed3;
#pragma unroll
    for (int r = 0; r < 16; ++r) wv0[r] = wv1[r];
  }
#undef EQOF
}

// ---------------------------------------------------------------------------
// LayerNorm over h (h = x + agg already)
// ---------------------------------------------------------------------------
__global__ __launch_bounds__(256) void ln_kernel(const float* __restrict__ hbuf,
                                                 const float* __restrict__ gamma,
                                                 const float* __restrict__ beta,
                                                 float* __restrict__ out, int N) {
  int wave = threadIdx.x >> 6, lane = threadIdx.x & 63;
  long row = (long)blockIdx.x * 4 + wave;
  if (row >= N) return;
  int c = lane * 2;
  f32x2 v = *(const f32x2*)&hbuf[row * D + c];
  float h0 = v.x, h1 = v.y;
  float sum = h0 + h1;
  float sq = h0 * h0 + h1 * h1;
#pragma unroll
  for (int o = 32; o; o >>= 1) {
    sum += __shfl_xor(sum, o, 64);
    sq += __shfl_xor(sq, o, 64);
  }
  float mu = sum * (1.0f / 128.0f);
  float var = sq * (1.0f / 128.0f) - mu * mu;
  float rstd = rsqrtf(var + 1e-5f);
  f32x2 gv = *(const f32x2*)&gamma[c];
  f32x2 bv = *(const f32x2*)&beta[c];
  f32x2 ov;
  ov.x = (h0 - mu) * rstd * gv.x + bv.x;
  ov.y = (h1 - mu) * rstd * gv.y + bv.y;
  *(f32x2*)&out[row * D + c] = ov;
}

// ---------------------------------------------------------------------------
extern "C" void kernel_launch(void* const* d_in, const int* in_sizes, int n_in,
                              void* d_out, int out_size, void* d_ws, size_t ws_size,
                              hipStream_t stream) {
  const float* x    = (const float*)d_in[0];
  const int*   gi   = (const int*)d_in[1];
  const int*   gj   = (const int*)d_in[2];
  const float* rbf  = (const float*)d_in[3];
  const float* Wl   = (const float*)d_in[4];
  const float* bl   = (const float*)d_in[5];
  const float* W0   = (const float*)d_in[6];
  const float* b0   = (const float*)d_in[7];
  const float* W2   = (const float*)d_in[8];
  const float* b2   = (const float*)d_in[9];
  const float* gam  = (const float*)d_in[10];
  const float* bet  = (const float*)d_in[11];

  const int N = in_sizes[0] / D;  // 50000
  const int E = in_sizes[1];      // 600000

  char* ws = (char*)d_ws;
  size_t off = 0;
  float* h    = (float*)(ws + off); off += (size_t)N * D * 4;
  short* WxhB = (short*)(ws + off); off += (size_t)N * D * 2;
  int4*  edat = (int4*)(ws + off);  off += (size_t)E * 16;
  int*   cnt  = (int*)(ws + off);   off += (size_t)N * 4;
  int*   pref = (int*)(ws + off);   off += (size_t)N * 4;
  int*   woff = (int*)(ws + off);   off += (size_t)N * 4;
  int*   bsum = (int*)(ws + off);   off += 1024;
  short* Wcb  = (short*)(ws + off); off += D * D * 2;
  short* W2b  = (short*)(ws + off); off += D * D * 2;

  const int ntiles = (E + 63) / 64;     // 64 edges per tile (4 waves x 16)
  const int nb = (N + 255) / 256;       // 196
  const int ngemm = (N + 63) / 64;      // 782

  prep_kernel<<<128 + nb + 512 + ngemm, 256, 0, stream>>>(
      W0, W2, x, Wl, bl, Wcb, W2b, cnt, h, WxhB, N, nb, (long)N * D / 4);
  hist_kernel<<<(E / 4 + 255) / 256, 256, 0, stream>>>(gi, cnt, E);
  scan_a_kernel<<<nb, 256, 0, stream>>>(cnt, pref, bsum, N);
  scan_c_kernel<<<nb, 256, 0, stream>>>(pref, bsum, woff, N);
  scatter_kernel<<<(E + 255) / 256, 256, 0, stream>>>(gi, gj, woff, edat, E);
  fused_edge_kernel<<<512, 256, 0, stream>>>(rbf, b0, b2, Wcb, W2b, WxhB,
                                             edat, h, E, ntiles);
  ln_kernel<<<(N + 3) / 4, 256, 0, stream>>>(h, gam, bet, (float*)d_out, N);
}